// Round 12
// baseline (605.979 us; speedup 1.0000x reference)
//
#include <hip/hip_runtime.h>
#include <cfloat>
#include <cmath>

#define DEV __device__ __forceinline__

constexpr int BB = 2, NN = 8192, KK = 16, CIN = 32, HH = 32, CO = 64, C2 = 128;
constexpr int BNTOT = BB * NN;        // 16384
constexpr int BNKROWS = BB * NN * KK; // 262144
constexpr float EPSF = 1e-6f;
constexpr int NCELL = 4096;           // 16^3 morton cells
constexpr int CAP = 128;              // survivor capacity per query (overflow -> exact fallback)

// stats indices (doubles): [sum.., sumsq..] per group
constexpr int S_LSE1 = 0, S_LSE2 = 64, S_ATT1 = 128, S_ATT2 = 192, S_SHORT = 320, S_TOTAL = 576;

// workspace layout (in floats)
constexpr size_t OFF_CP4   = 0;                                  // orig-order (x,y,z,sq): 16384*4
constexpr size_t OFF_SE    = OFF_CP4 + (size_t)BNTOT * 4;        // se (B,N,K,10)
constexpr size_t OFF_XF    = OFF_SE + (size_t)BNKROWS * 10;      // mlp1 out (B,N,32)
constexpr size_t OFF_SHORT = OFF_XF + (size_t)BNTOT * HH;        // shortcut pre-BN (B,N,128)
constexpr size_t OFF_PRE1  = OFF_SHORT + (size_t)BNTOT * C2;     // att1 pre-BN (B,N,32)
constexpr size_t OFF_PRE2  = OFF_PRE1 + (size_t)BNTOT * HH;      // att2 pre-BN (B,N,64)
constexpr size_t OFF_STATS = OFF_PRE2 + (size_t)BNTOT * CO;      // doubles x576 (even -> 8B aligned)
constexpr size_t OFF_COUNTS= OFF_STATS + 2 * S_TOTAL;            // int[2][4096]
constexpr size_t OFF_TB    = OFF_COUNTS + 2 * NCELL;             // float[16384] T_q bounds
// sort scratch overlaid in SHORT region (dead until k_feat, which runs after k_knn)
constexpr size_t OFF_CODE  = OFF_SHORT;                          // int[16384]
constexpr size_t OFF_CPS   = OFF_CODE + 16384;                   // float4[2][8192] + 4 pad
constexpr size_t OFF_OIDX  = OFF_CPS + (size_t)BNTOT * 4 + 16;   // int[2][8192]

DEV unsigned spr3(unsigned v) {
    return (v & 1u) | ((v & 2u) << 2) | ((v & 4u) << 4) | ((v & 8u) << 6);
}

// ---------------- K0: pack (x,y,z,sq) + morton cell + counts ----------------
__global__ __launch_bounds__(256) void k_prep(const float* __restrict__ coords,
                                              float4* __restrict__ cp4,
                                              int* __restrict__ code, int* __restrict__ counts) {
#pragma clang fp contract(off)
    int i = blockIdx.x * 256 + threadIdx.x;
    if (i >= BNTOT) return;
    float x = coords[3 * i], y = coords[3 * i + 1], z = coords[3 * i + 2];
    float sq = (x * x + y * y) + z * z;   // match numpy sum order, no FMA
    cp4[i] = make_float4(x, y, z, sq);
    const float inv = 16.f / 8.8f;
    int ix = min(15, max(0, (int)floorf((x + 4.4f) * inv)));
    int iy = min(15, max(0, (int)floorf((y + 4.4f) * inv)));
    int iz = min(15, max(0, (int)floorf((z + 4.4f) * inv)));
    unsigned m = spr3(ix) | (spr3(iy) << 1) | (spr3(iz) << 2);
    code[i] = (int)m;
    atomicAdd(&counts[((i >> 13) << 12) + m], 1);
}

// ---------------- K0b: exclusive prefix scan of counts (per batch) ----------------
__global__ __launch_bounds__(256) void k_scan(int* __restrict__ counts) {
    __shared__ int lds[256];
    int t = threadIdx.x;
    for (int b = 0; b < 2; ++b) {
        int base = b * NCELL;
        int v[16]; int s = 0;
#pragma unroll
        for (int k = 0; k < 16; ++k) { int tmp = counts[base + t * 16 + k]; v[k] = s; s += tmp; }
        lds[t] = s;
        __syncthreads();
        for (int o = 1; o < 256; o <<= 1) {
            int u = (t >= o) ? lds[t - o] : 0;
            __syncthreads();
            lds[t] += u;
            __syncthreads();
        }
        int off = lds[t] - s;   // exclusive
#pragma unroll
        for (int k = 0; k < 16; ++k) counts[base + t * 16 + k] = off + v[k];
        __syncthreads();
    }
}

// ---------------- K0c: scatter into sorted order ----------------
__global__ __launch_bounds__(256) void k_scatter(const float4* __restrict__ cp4,
                                                 const int* __restrict__ code,
                                                 int* __restrict__ cursor,
                                                 float4* __restrict__ cps, int* __restrict__ oidx) {
    int i = blockIdx.x * 256 + threadIdx.x;
    if (i >= BNTOT) return;
    int b = i >> 13, n = i & 8191;
    int c = code[i];
    int pos = atomicAdd(&cursor[(b << 12) + c], 1);
    cps[(b << 13) + pos] = cp4[i];
    oidx[(b << 13) + pos] = n;
}

DEV float dist2(float4 qc, float4 c) {
#pragma clang fp contract(off)
    float dot = (qc.x * c.x + qc.y * c.y) + qc.z * c.z;
    return (qc.w + c.w) - 2.0f * dot;   // exact jax/np expansion formula
}

// value-only sorted insert (16-deep): keeps 16 smallest values
DEV void insv16(float (&dl)[16], float d) {
    float dk = d;
#pragma unroll
    for (int r = 0; r < 16; ++r) {
        bool c = dk < dl[r];
        float td = dl[r];
        dl[r] = c ? dk : dl[r];
        dk = c ? td : dk;
    }
}

// lexicographic (d, idx) sorted insert
DEV void ins16_lex(float (&dl)[16], int (&il)[16], float d, int id) {
    float dk = d; int jk = id;
#pragma unroll
    for (int r = 0; r < 16; ++r) {
        bool c = (dk < dl[r]) || (dk == dl[r] && jk < il[r]);
        float td = dl[r]; int ti = il[r];
        dl[r] = c ? dk : dl[r]; il[r] = c ? jk : il[r];
        dk = c ? td : dk; jk = c ? ti : jk;
    }
}

// ---------------- K0d: per-query threshold bound from 256 Morton-window neighbors ----
// T_q = 16th-smallest exact d2 among the query's 256 sorted-order neighbors.
// Subset 16th order-stat >= global 16th order-stat -> EXACT upper bound, no margin.
// (Bound can be LOOSE where the Morton curve jumps; k_knn's fallback handles that.)
__global__ __launch_bounds__(256) void k_seed(const float4* __restrict__ cps,
                                              const int* __restrict__ oidx,
                                              float* __restrict__ tbound) {
    int g = blockIdx.x * 256 + threadIdx.x;
    int b = g >> 13, p = g & 8191;
    const float4* cb_ = cps + ((size_t)b << 13);
    float4 qc = cb_[p];
    int s = p - 128;
    s = s < 0 ? 0 : (s > NN - 256 ? NN - 256 : s);
    float dl[16];
#pragma unroll
    for (int i = 0; i < 16; ++i) dl[i] = FLT_MAX;
    for (int j = 0; j < 256; j += 4) {
        float4 c0 = cb_[s + j], c1 = cb_[s + j + 1], c2 = cb_[s + j + 2], c3 = cb_[s + j + 3];
        float d0 = dist2(qc, c0), d1 = dist2(qc, c1), d2v = dist2(qc, c2), d3 = dist2(qc, c3);
        if (d0 < dl[15]) insv16(dl, d0);
        if (d1 < dl[15]) insv16(dl, d1);
        if (d2v < dl[15]) insv16(dl, d2v);
        if (d3 < dl[15]) insv16(dl, d3);
    }
    tbound[(b << 13) + oidx[(b << 13) + p]] = dl[15];
}

// ---------------- K1: bound-filter KNN + exact select + spatial encoding ----------------
// grid 1024 = 2 batches x 512 groups of 16 queries; block 256; thread: query=t&15,
// partition=t>>4 (16 x 512 candidates, original order). NO in-scan selection:
// predicate d <= T_q -> append survivor (d,idx) to LDS. scnt counts ALL survivors;
// queries whose count exceeds CAP (loose T at Morton jumps — R11 failure mode) are
// recomputed EXACTLY by one wave (64-lane scan + shfl butterfly top-16 merge), so
// truncation is never observable. Both paths: exact lex-(d2, idx) top-16 ==
// jax top_k semantics; both are set-determined -> deterministic despite atomics.
__global__ __launch_bounds__(256) void k_knn(const float4* __restrict__ cp4,
                                             const float* __restrict__ tbound,
                                             float* __restrict__ se) {
    __shared__ uint2 surv[16][CAP + 1];   // +1 col pad -> phase-C reads spread banks
    __shared__ int scnt[16];
    __shared__ float sd[16][17];
    __shared__ int   si[16][17];

    int t = threadIdx.x;
    int b = blockIdx.x >> 9;
    int qbase = (blockIdx.x & 511) * 16;
    int ql = t & 15, part = t >> 4;
    int wv = t >> 6, lane = t & 63;
    const float4* cp = cp4 + ((size_t)b << 13);
    int q = qbase + ql;
    float4 qc = cp[q];
    float T = tbound[(b << 13) + q];

    if (t < 16) scnt[t] = 0;
    __syncthreads();

    int cb = part * 512;
    // prefetched flat scan; pure filter
    float4 n0 = cp[cb], n1 = cp[cb + 1], n2 = cp[cb + 2], n3 = cp[cb + 3];
    for (int j = cb; j < cb + 512; j += 4) {
        float4 c0 = n0, c1 = n1, c2 = n2, c3 = n3;
        n0 = cp[j + 4]; n1 = cp[j + 5]; n2 = cp[j + 6]; n3 = cp[j + 7]; // tail over-read lands in ws (se region), unused
        float d0 = dist2(qc, c0), d1 = dist2(qc, c1), d2v = dist2(qc, c2), d3 = dist2(qc, c3);
        bool p0 = d0 <= T, p1 = d1 <= T, p2 = d2v <= T, p3 = d3 <= T;
        if (__any(p0 | p1 | p2 | p3)) {
            if (p0) { int pos = atomicAdd(&scnt[ql], 1); if (pos < CAP) surv[ql][pos] = make_uint2(__float_as_uint(d0), (unsigned)j); }
            if (p1) { int pos = atomicAdd(&scnt[ql], 1); if (pos < CAP) surv[ql][pos] = make_uint2(__float_as_uint(d1), (unsigned)(j + 1)); }
            if (p2) { int pos = atomicAdd(&scnt[ql], 1); if (pos < CAP) surv[ql][pos] = make_uint2(__float_as_uint(d2v), (unsigned)(j + 2)); }
            if (p3) { int pos = atomicAdd(&scnt[ql], 1); if (pos < CAP) surv[ql][pos] = make_uint2(__float_as_uint(d3), (unsigned)(j + 3)); }
        }
    }
    __syncthreads();

    // fallback: exact wave-parallel top-16 for overflowed queries (rare; wave-uniform branch)
    for (int q2 = wv; q2 < 16; q2 += 4) {
        if (scnt[q2] > CAP) {
            float4 qc2 = cp[qbase + q2];
            float dl[16]; int il[16];
#pragma unroll
            for (int i = 0; i < 16; ++i) { dl[i] = FLT_MAX; il[i] = 0x7fffffff; }
            for (int i = 0; i < 128; ++i) {       // coalesced: lane + 64*i
                int j = lane + (i << 6);
                float d = dist2(qc2, cp[j]);
                if (d < dl[15] || (d == dl[15] && j < il[15])) ins16_lex(dl, il, d, j);
            }
            // 6-round butterfly: after round r each lane holds top-16 of 2^(r+1) lanes' union
            for (int o = 1; o < 64; o <<= 1) {
                float dd[16]; int ii[16];
#pragma unroll
                for (int i = 0; i < 16; ++i) { dd[i] = __shfl_xor(dl[i], o); ii[i] = __shfl_xor(il[i], o); }
#pragma unroll
                for (int i = 0; i < 16; ++i) {
                    if (dd[i] < dl[15] || (dd[i] == dl[15] && ii[i] < il[15])) ins16_lex(dl, il, dd[i], ii[i]);
                }
            }
            if (lane == 0) {
#pragma unroll
                for (int i = 0; i < 16; ++i) { sd[q2][i] = dl[i]; si[q2][i] = il[i]; }
            }
        }
    }

    // phase C: exact lex top-16 of survivors (one thread per query, non-overflowed only)
    if (t < 16 && scnt[t] <= CAP) {
        int n = scnt[t];
        float dl[16]; int il[16];
#pragma unroll
        for (int i = 0; i < 16; ++i) { dl[i] = FLT_MAX; il[i] = 0x7fffffff; }
        for (int s2 = 0; s2 < n; ++s2) {
            uint2 v = surv[t][s2];
            float d = __uint_as_float(v.x); int id = (int)v.y;
            if (d < dl[15] || (d == dl[15] && id < il[15])) ins16_lex(dl, il, d, id);
        }
#pragma unroll
        for (int i = 0; i < 16; ++i) { sd[t][i] = dl[i]; si[t][i] = il[i]; }
    }
    __syncthreads();

    // epilogue: 256 threads write 256 se rows (one (q,k) slot each)
    {
        int qq = t >> 4, k = t & 15;
        float d2s = sd[qq][k]; int id = si[qq][k];
        float4 qc2 = cp[qbase + qq];
        float4 nb = cp[id];
        float dist = sqrtf(fmaxf(d2s, 1e-12f));
        float* sp = se + ((size_t)(b * NN + qbase + qq) * KK + k) * 10;
        sp[0] = qc2.x; sp[1] = qc2.y; sp[2] = qc2.z;
        sp[3] = nb.x;  sp[4] = nb.y;  sp[5] = nb.z;
        sp[6] = qc2.x - nb.x; sp[7] = qc2.y - nb.y; sp[8] = qc2.z - nb.z;
        sp[9] = dist;
    }
}

// ---------------- K2: mlp1 + shortcut linear + shortcut BN stats ----------------
__global__ __launch_bounds__(128) void k_feat(const float* __restrict__ feat,
                                              const float* __restrict__ Wm1, const float* __restrict__ bm1,
                                              const float* __restrict__ Wsh, const float* __restrict__ bsh,
                                              float* __restrict__ xf, float* __restrict__ short_pre,
                                              double* __restrict__ stats) {
    __shared__ float fl[32][33];
    int t = threadIdx.x;
    int pbase = blockIdx.x * 32;
    float wcol[32];
#pragma unroll
    for (int i = 0; i < 32; ++i) wcol[i] = Wsh[i * C2 + t];
    float wm[32];
    if (t < 32) {
#pragma unroll
        for (int i = 0; i < 32; ++i) wm[i] = Wm1[i * HH + t];
    }
    float bs = bsh[t];
    float bm = (t < 32) ? bm1[t] : 0.f;
    double s = 0.0, s2 = 0.0;

    for (int e = t; e < 1024; e += 128) {
        int p = e >> 5, i = e & 31;
        fl[p][i] = feat[(size_t)(pbase + p) * CIN + i];
    }
    __syncthreads();
    for (int p = 0; p < 32; ++p) {
        float acc = bs;
#pragma unroll
        for (int i = 0; i < 32; ++i) acc += fl[p][i] * wcol[i];
        int gp = pbase + p;
        short_pre[(size_t)gp * C2 + t] = acc;
        s += acc; s2 += (double)acc * acc;
        if (t < 32) {
            float xv = bm;
#pragma unroll
            for (int i = 0; i < 32; ++i) xv += fl[p][i] * wm[i];
            xf[(size_t)gp * HH + t] = xv >= 0.f ? xv : 0.2f * xv;
        }
    }
    atomicAdd(&stats[S_SHORT + t], s);
    atomicAdd(&stats[S_SHORT + C2 + t], s2);
}

// ---------------- K3: lse1+lse2 linear BN stats (LDS-staged) ----------------
__global__ __launch_bounds__(256) void k_lse_stats(const float* __restrict__ se,
                                                   const float* __restrict__ W1, const float* __restrict__ b1,
                                                   const float* __restrict__ W2, const float* __restrict__ b2,
                                                   double* __restrict__ stats) {
    __shared__ float srows[256][10];
    __shared__ double red[4][64][2];
    int t = threadIdx.x;
    int c = t & 63, grp = t >> 6;
    int ch = c & 31; bool second = c >= 32;
    const float* W = second ? W2 : W1;
    float wcol[10];
#pragma unroll
    for (int d = 0; d < 10; ++d) wcol[d] = W[d * HH + ch];
    float bb = second ? b2[ch] : b1[ch];
    double s = 0.0, s2 = 0.0;
    int rbase = blockIdx.x * 512;

    for (int tile = 0; tile < 2; ++tile) {
        __syncthreads();
        const float* src = se + (size_t)(rbase + tile * 256) * 10;
        for (int e = t; e < 2560; e += 256) srows[e / 10][e % 10] = src[e];
        __syncthreads();
        int r0 = grp * 64;
        for (int r = r0; r < r0 + 64; ++r) {
            float acc = bb;
#pragma unroll
            for (int d = 0; d < 10; ++d) acc += srows[r][d] * wcol[d];
            s += acc; s2 += (double)acc * acc;
        }
    }
    red[grp][c][0] = s; red[grp][c][1] = s2;
    __syncthreads();
    if (grp == 0) {
        for (int g = 1; g < 4; ++g) { s += red[g][c][0]; s2 += red[g][c][1]; }
        int base = second ? S_LSE2 : S_LSE1;
        atomicAdd(&stats[base + ch], s);
        atomicAdd(&stats[base + 32 + ch], s2);
    }
}

// BN scale/shift from raw stats (computed redundantly in consumer prologues)
DEV float2 fin_pair(const double* stats, int sbase, int ch, int nch, double M,
                    const float* g, const float* be) {
    double mean = stats[sbase + ch] / M;
    double var = stats[sbase + nch + ch] / M - mean * mean;
    double scd = (double)g[ch] / sqrt(var + (double)EPSF);
    return make_float2((float)scd, (float)((double)be[ch] - mean * scd));
}

// ---------------- K5/K7: fused LocSE + attentive pooling + MLP ----------------
template <int OUTC, bool SECOND>
__global__ __launch_bounds__(256) void k_att(const float* __restrict__ se,
                                             const float* __restrict__ featsrc,
                                             const float* __restrict__ Wlse, const float* __restrict__ blse,
                                             const float* __restrict__ Wlin,
                                             const float* __restrict__ Wmlp, const float* __restrict__ bmlp,
                                             double* __restrict__ stats, int lse_sbase, int feat_sbase, int stat_base,
                                             const float* __restrict__ g_lse, const float* __restrict__ be_lse,
                                             const float* __restrict__ g_f, const float* __restrict__ be_f,
                                             float* __restrict__ preout) {
    __shared__ __align__(16) float wlt[64][68];
    __shared__ float wm[64][OUTC];
    __shared__ __align__(16) float x1[4][16][40];
    __shared__ float fv[4][32];
    __shared__ float p1b[4][64];
    __shared__ double red[4][OUTC][2];

    int t = threadIdx.x, w = t >> 6, c = t & 63;
    int ch = c & 31, half = c >> 5;
    for (int e = t; e < 4096; e += 256) wlt[e & 63][e >> 6] = Wlin[e];
    for (int e = t; e < 64 * OUTC; e += 256) wm[e / OUTC][e % OUTC] = Wmlp[e];

    float wf[10]; float bf;
    {
        float2 p = fin_pair(stats, lse_sbase, ch, 32, (double)BNKROWS, g_lse, be_lse);
#pragma unroll
        for (int d = 0; d < 10; ++d) wf[d] = Wlse[d * 32 + ch] * p.x;
        bf = blse[ch] * p.x + p.y;
    }
    float fa = 1.f, fb = 0.f;
    if (SECOND && c >= 32) {
        float2 p = fin_pair(stats, feat_sbase, ch, 32, (double)BNTOT, g_f, be_f);
        fa = p.x; fb = p.y;
    }
    double s = 0.0, s2 = 0.0;
    __syncthreads();

    for (int i = 0; i < 4; ++i) {
        int p = blockIdx.x * 16 + w * 4 + i;

        int kbase = half * 8;
        const float* sp = se + (size_t)p * (KK * 10) + kbase * 10;
        float myv[8];
#pragma unroll
        for (int kk = 0; kk < 8; ++kk) {
            float acc = bf;
#pragma unroll
            for (int d = 0; d < 10; ++d) acc += sp[kk * 10 + d] * wf[d];
            myv[kk] = fmaxf(acc, 0.f);
        }
#pragma unroll
        for (int kk = 0; kk < 8; ++kk) x1[w][kbase + kk][ch] = myv[kk];

        float xv = 0.f;
        if (c >= 32) {
            xv = featsrc[(size_t)p * 32 + ch];
            if (SECOND) xv = fmaxf(xv * fa + fb, 0.f);
            fv[w][ch] = xv;
        }

        float col[16];
        if (c < 32) {
#pragma unroll
            for (int kk = 0; kk < 8; ++kk) col[kk] = myv[kk];
#pragma unroll
            for (int kk = 0; kk < 8; ++kk) col[8 + kk] = x1[w][8 + kk][ch];
        } else {
#pragma unroll
            for (int k = 0; k < 16; ++k) col[k] = xv;
        }

        float cst = 0.f;
#pragma unroll
        for (int dg = 8; dg < 16; ++dg) {
            float4 wv = *(const float4*)&wlt[c][dg * 4];
            float4 xvv = *(const float4*)&fv[w][(dg - 8) * 4];
            cst += xvv.x * wv.x + xvv.y * wv.y + xvv.z * wv.z + xvv.w * wv.w;
        }
        float scv[16];
#pragma unroll
        for (int k = 0; k < 16; ++k) scv[k] = cst;
        for (int dg = 0; dg < 8; ++dg) {
            float4 wv = *(const float4*)&wlt[c][dg * 4];
#pragma unroll
            for (int k = 0; k < 16; ++k) {
                float4 xvv = *(const float4*)&x1[w][k][dg * 4];
                scv[k] += xvv.x * wv.x + xvv.y * wv.y + xvv.z * wv.z + xvv.w * wv.w;
            }
        }
        float m = scv[0];
#pragma unroll
        for (int k = 1; k < 16; ++k) m = fmaxf(m, scv[k]);
        float sum = 0.f, p1 = 0.f;
#pragma unroll
        for (int k = 0; k < 16; ++k) { float e = __expf(scv[k] - m); sum += e; p1 += e * col[k]; }
        p1 /= sum;
        p1b[w][c] = p1;

        if (c < OUTC) {
            float acc = bmlp[c];
#pragma unroll
            for (int d = 0; d < 64; ++d) acc += p1b[w][d] * wm[d][c];
            preout[(size_t)p * OUTC + c] = acc;
            s += acc; s2 += (double)acc * acc;
        }
    }
    if (c < OUTC) { red[w][c][0] = s; red[w][c][1] = s2; }
    __syncthreads();
    if (t < OUTC) {
        double ts = red[0][t][0], ts2 = red[0][t][1];
        for (int g = 1; g < 4; ++g) { ts += red[g][t][0]; ts2 += red[g][t][1]; }
        atomicAdd(&stats[stat_base + t], ts);
        atomicAdd(&stats[stat_base + OUTC + t], ts2);
    }
}

// ---------------- K9: final mlp2 + shortcut BN + residual leaky + transposed write ----
__global__ __launch_bounds__(256) void k_out(const float* __restrict__ pre2,
                                             const float* __restrict__ short_pre,
                                             const float* __restrict__ W2, const float* __restrict__ b2,
                                             const double* __restrict__ stats,
                                             const float* __restrict__ g_a2, const float* __restrict__ be_a2,
                                             const float* __restrict__ g_s, const float* __restrict__ be_s,
                                             float* __restrict__ out) {
    __shared__ __align__(16) float w2[64][128];
    __shared__ float sc2[64], sh2[64], scs[128], shs[128], bb[128];
    int t = threadIdx.x;
    int pl = t & 31, seg = t >> 5;
    for (int e = t; e < 8192; e += 256) w2[e >> 7][e & 127] = W2[e];
    if (t < 64) { float2 p = fin_pair(stats, S_ATT2, t, 64, (double)BNTOT, g_a2, be_a2); sc2[t] = p.x; sh2[t] = p.y; }
    if (t >= 64 && t < 192) { int ch = t - 64; float2 p = fin_pair(stats, S_SHORT, ch, 128, (double)BNTOT, g_s, be_s); scs[ch] = p.x; shs[ch] = p.y; }
    if (t < 128) bb[t] = b2[t];
    __syncthreads();

    int p = blockIdx.x * 32 + pl;
    int b = p >> 13, n = p & 8191;
    const float* pr = pre2 + (size_t)p * 64;
    float xa[64];
#pragma unroll
    for (int c = 0; c < 64; c += 4) {
        float4 v = *(const float4*)&pr[c];
        xa[c + 0] = fmaxf(v.x * sc2[c + 0] + sh2[c + 0], 0.f);
        xa[c + 1] = fmaxf(v.y * sc2[c + 1] + sh2[c + 1], 0.f);
        xa[c + 2] = fmaxf(v.z * sc2[c + 2] + sh2[c + 2], 0.f);
        xa[c + 3] = fmaxf(v.w * sc2[c + 3] + sh2[c + 3], 0.f);
    }
    const float* shp = short_pre + (size_t)p * 128;
    int obase = seg * 16;
    for (int o = obase; o < obase + 16; o += 4) {
        float a0 = bb[o], a1 = bb[o + 1], a2 = bb[o + 2], a3 = bb[o + 3];
#pragma unroll
        for (int cc = 0; cc < 64; ++cc) {
            float4 wv = *(const float4*)&w2[cc][o];
            float x = xa[cc];
            a0 += x * wv.x; a1 += x * wv.y; a2 += x * wv.z; a3 += x * wv.w;
        }
        float4 sv = *(const float4*)&shp[o];
        float r0 = a0 + (sv.x * scs[o] + shs[o]);
        float r1 = a1 + (sv.y * scs[o + 1] + shs[o + 1]);
        float r2 = a2 + (sv.z * scs[o + 2] + shs[o + 2]);
        float r3 = a3 + (sv.w * scs[o + 3] + shs[o + 3]);
        out[((size_t)(b * C2 + o + 0)) * NN + n] = r0 >= 0.f ? r0 : 0.01f * r0;
        out[((size_t)(b * C2 + o + 1)) * NN + n] = r1 >= 0.f ? r1 : 0.01f * r1;
        out[((size_t)(b * C2 + o + 2)) * NN + n] = r2 >= 0.f ? r2 : 0.01f * r2;
        out[((size_t)(b * C2 + o + 3)) * NN + n] = r3 >= 0.f ? r3 : 0.01f * r3;
    }
}

extern "C" void kernel_launch(void* const* d_in, const int* in_sizes, int n_in,
                              void* d_out, int out_size, void* d_ws, size_t ws_size,
                              hipStream_t stream) {
    const float* coords    = (const float*)d_in[0];
    const float* features  = (const float*)d_in[1];
    const float* W_mlp1    = (const float*)d_in[2];
    const float* b_mlp1    = (const float*)d_in[3];
    const float* W_lse1    = (const float*)d_in[4];
    const float* b_lse1    = (const float*)d_in[5];
    const float* g_lse1    = (const float*)d_in[6];
    const float* be_lse1   = (const float*)d_in[7];
    const float* W_att1_lin= (const float*)d_in[8];
    const float* W_att1_mlp= (const float*)d_in[9];
    const float* b_att1_mlp= (const float*)d_in[10];
    const float* g_att1    = (const float*)d_in[11];
    const float* be_att1   = (const float*)d_in[12];
    const float* W_lse2    = (const float*)d_in[13];
    const float* b_lse2    = (const float*)d_in[14];
    const float* g_lse2    = (const float*)d_in[15];
    const float* be_lse2   = (const float*)d_in[16];
    const float* W_att2_lin= (const float*)d_in[17];
    const float* W_att2_mlp= (const float*)d_in[18];
    const float* b_att2_mlp= (const float*)d_in[19];
    const float* g_att2    = (const float*)d_in[20];
    const float* be_att2   = (const float*)d_in[21];
    const float* W_mlp2    = (const float*)d_in[22];
    const float* b_mlp2    = (const float*)d_in[23];
    const float* W_short   = (const float*)d_in[24];
    const float* b_short   = (const float*)d_in[25];
    const float* g_short   = (const float*)d_in[26];
    const float* be_short  = (const float*)d_in[27];

    float* ws = (float*)d_ws;
    float4* cp4      = (float4*)(ws + OFF_CP4);
    float* se        = ws + OFF_SE;
    float* xf        = ws + OFF_XF;
    float* short_pre = ws + OFF_SHORT;
    float* pre1      = ws + OFF_PRE1;
    float* pre2      = ws + OFF_PRE2;
    double* stats    = (double*)(ws + OFF_STATS);
    int* counts      = (int*)(ws + OFF_COUNTS);
    float* tbound    = ws + OFF_TB;
    int* code        = (int*)(ws + OFF_CODE);
    float4* cps      = (float4*)(ws + OFF_CPS);
    int* oidxArr     = (int*)(ws + OFF_OIDX);
    float* out       = (float*)d_out;

    // zero stats (576 doubles) + counts (8192 ints), contiguous
    hipMemsetAsync(stats, 0, S_TOTAL * 8 + 2 * NCELL * 4, stream);

    k_prep<<<BNTOT / 256, 256, 0, stream>>>(coords, cp4, code, counts);
    k_scan<<<1, 256, 0, stream>>>(counts);
    k_scatter<<<BNTOT / 256, 256, 0, stream>>>(cp4, code, counts, cps, oidxArr);
    k_seed<<<BNTOT / 256, 256, 0, stream>>>(cps, oidxArr, tbound);
    k_knn<<<1024, 256, 0, stream>>>(cp4, tbound, se);
    k_feat<<<512, 128, 0, stream>>>(features, W_mlp1, b_mlp1, W_short, b_short,
                                    xf, short_pre, stats);
    k_lse_stats<<<512, 256, 0, stream>>>(se, W_lse1, b_lse1, W_lse2, b_lse2, stats);
    k_att<32, false><<<1024, 256, 0, stream>>>(se, xf, W_lse1, b_lse1, W_att1_lin,
                                               W_att1_mlp, b_att1_mlp, stats,
                                               S_LSE1, 0, S_ATT1,
                                               g_lse1, be_lse1, nullptr, nullptr, pre1);
    k_att<64, true><<<1024, 256, 0, stream>>>(se, pre1, W_lse2, b_lse2, W_att2_lin,
                                              W_att2_mlp, b_att2_mlp, stats,
                                              S_LSE2, S_ATT1, S_ATT2,
                                              g_lse2, be_lse2, g_att1, be_att1, pre2);
    k_out<<<BNTOT / 32, 256, 0, stream>>>(pre2, short_pre, W_mlp2, b_mlp2, stats,
                                          g_att2, be_att2, g_short, be_short, out);
}

// Round 13
// 592.071 us; speedup vs baseline: 1.0235x; 1.0235x over previous
//
#include <hip/hip_runtime.h>
#include <cfloat>
#include <cmath>

#define DEV __device__ __forceinline__

constexpr int BB = 2, NN = 8192, KK = 16, CIN = 32, HH = 32, CO = 64, C2 = 128;
constexpr int BNTOT = BB * NN;        // 16384
constexpr int BNKROWS = BB * NN * KK; // 262144
constexpr float EPSF = 1e-6f;
constexpr int NCELL = 4096;           // 16^3 morton cells
constexpr int CAP = 128;              // survivor capacity per query (overflow -> exact fallback)

// stats indices (doubles): [sum.., sumsq..] per group
constexpr int S_LSE1 = 0, S_LSE2 = 64, S_ATT1 = 128, S_ATT2 = 192, S_SHORT = 320, S_TOTAL = 576;

// workspace layout (in floats)
constexpr size_t OFF_CP4   = 0;                                  // orig-order (x,y,z,sq): 16384*4
constexpr size_t OFF_SE    = OFF_CP4 + (size_t)BNTOT * 4;        // se (B,N,K,10)
constexpr size_t OFF_XF    = OFF_SE + (size_t)BNKROWS * 10;      // mlp1 out (B,N,32)
constexpr size_t OFF_SHORT = OFF_XF + (size_t)BNTOT * HH;        // shortcut pre-BN (B,N,128)
constexpr size_t OFF_PRE1  = OFF_SHORT + (size_t)BNTOT * C2;     // att1 pre-BN (B,N,32)
constexpr size_t OFF_PRE2  = OFF_PRE1 + (size_t)BNTOT * HH;      // att2 pre-BN (B,N,64)
constexpr size_t OFF_STATS = OFF_PRE2 + (size_t)BNTOT * CO;      // doubles x576 (even -> 8B aligned)
constexpr size_t OFF_COUNTS= OFF_STATS + 2 * S_TOTAL;            // int[2][4096]
constexpr size_t OFF_TB    = OFF_COUNTS + 2 * NCELL;             // float[16384] T_q bounds
// sort scratch overlaid in SHORT region (dead until k_feat, which runs after k_knn)
constexpr size_t OFF_CODE  = OFF_SHORT;                          // int[16384]
constexpr size_t OFF_CPS   = OFF_CODE + 16384;                   // float4[2][8192] + 4 pad
constexpr size_t OFF_OIDX  = OFF_CPS + (size_t)BNTOT * 4 + 16;   // int[2][8192]

DEV unsigned spr3(unsigned v) {
    return (v & 1u) | ((v & 2u) << 2) | ((v & 4u) << 4) | ((v & 8u) << 6);
}

// ---------------- K0: pack (x,y,z,sq) + morton cell + counts ----------------
__global__ __launch_bounds__(256) void k_prep(const float* __restrict__ coords,
                                              float4* __restrict__ cp4,
                                              int* __restrict__ code, int* __restrict__ counts) {
#pragma clang fp contract(off)
    int i = blockIdx.x * 256 + threadIdx.x;
    if (i >= BNTOT) return;
    float x = coords[3 * i], y = coords[3 * i + 1], z = coords[3 * i + 2];
    float sq = (x * x + y * y) + z * z;   // match numpy sum order, no FMA
    cp4[i] = make_float4(x, y, z, sq);
    const float inv = 16.f / 8.8f;
    int ix = min(15, max(0, (int)floorf((x + 4.4f) * inv)));
    int iy = min(15, max(0, (int)floorf((y + 4.4f) * inv)));
    int iz = min(15, max(0, (int)floorf((z + 4.4f) * inv)));
    unsigned m = spr3(ix) | (spr3(iy) << 1) | (spr3(iz) << 2);
    code[i] = (int)m;
    atomicAdd(&counts[((i >> 13) << 12) + m], 1);
}

// ---------------- K0b: exclusive prefix scan of counts (per batch) ----------------
__global__ __launch_bounds__(256) void k_scan(int* __restrict__ counts) {
    __shared__ int lds[256];
    int t = threadIdx.x;
    for (int b = 0; b < 2; ++b) {
        int base = b * NCELL;
        int v[16]; int s = 0;
#pragma unroll
        for (int k = 0; k < 16; ++k) { int tmp = counts[base + t * 16 + k]; v[k] = s; s += tmp; }
        lds[t] = s;
        __syncthreads();
        for (int o = 1; o < 256; o <<= 1) {
            int u = (t >= o) ? lds[t - o] : 0;
            __syncthreads();
            lds[t] += u;
            __syncthreads();
        }
        int off = lds[t] - s;   // exclusive
#pragma unroll
        for (int k = 0; k < 16; ++k) counts[base + t * 16 + k] = off + v[k];
        __syncthreads();
    }
}

// ---------------- K0c: scatter into sorted order ----------------
__global__ __launch_bounds__(256) void k_scatter(const float4* __restrict__ cp4,
                                                 const int* __restrict__ code,
                                                 int* __restrict__ cursor,
                                                 float4* __restrict__ cps, int* __restrict__ oidx) {
    int i = blockIdx.x * 256 + threadIdx.x;
    if (i >= BNTOT) return;
    int b = i >> 13, n = i & 8191;
    int c = code[i];
    int pos = atomicAdd(&cursor[(b << 12) + c], 1);
    cps[(b << 13) + pos] = cp4[i];
    oidx[(b << 13) + pos] = n;
}

DEV float dist2(float4 qc, float4 c) {
#pragma clang fp contract(off)
    float dot = (qc.x * c.x + qc.y * c.y) + qc.z * c.z;
    return (qc.w + c.w) - 2.0f * dot;   // exact jax/np expansion formula
}

// value-only sorted insert (16-deep): keeps 16 smallest values
DEV void insv16(float (&dl)[16], float d) {
    float dk = d;
#pragma unroll
    for (int r = 0; r < 16; ++r) {
        bool c = dk < dl[r];
        float td = dl[r];
        dl[r] = c ? dk : dl[r];
        dk = c ? td : dk;
    }
}

// lexicographic (d, idx) sorted insert
DEV void ins16_lex(float (&dl)[16], int (&il)[16], float d, int id) {
    float dk = d; int jk = id;
#pragma unroll
    for (int r = 0; r < 16; ++r) {
        bool c = (dk < dl[r]) || (dk == dl[r] && jk < il[r]);
        float td = dl[r]; int ti = il[r];
        dl[r] = c ? dk : dl[r]; il[r] = c ? jk : il[r];
        dk = c ? td : dk; jk = c ? ti : jk;
    }
}

// ---------------- K0d: per-query threshold bound from 256 Morton-window neighbors ----
// T_q = 16th-smallest exact d2 among the query's 256 sorted-order neighbors.
// Subset 16th order-stat >= global 16th order-stat -> EXACT upper bound, no margin.
// (Bound can be LOOSE where the Morton curve jumps; k_knn's fallback handles that.)
__global__ __launch_bounds__(256) void k_seed(const float4* __restrict__ cps,
                                              const int* __restrict__ oidx,
                                              float* __restrict__ tbound) {
    int g = blockIdx.x * 256 + threadIdx.x;
    int b = g >> 13, p = g & 8191;
    const float4* cb_ = cps + ((size_t)b << 13);
    float4 qc = cb_[p];
    int s = p - 128;
    s = s < 0 ? 0 : (s > NN - 256 ? NN - 256 : s);
    float dl[16];
#pragma unroll
    for (int i = 0; i < 16; ++i) dl[i] = FLT_MAX;
    for (int j = 0; j < 256; j += 4) {
        float4 c0 = cb_[s + j], c1 = cb_[s + j + 1], c2 = cb_[s + j + 2], c3 = cb_[s + j + 3];
        float d0 = dist2(qc, c0), d1 = dist2(qc, c1), d2v = dist2(qc, c2), d3 = dist2(qc, c3);
        if (d0 < dl[15]) insv16(dl, d0);
        if (d1 < dl[15]) insv16(dl, d1);
        if (d2v < dl[15]) insv16(dl, d2v);
        if (d3 < dl[15]) insv16(dl, d3);
    }
    tbound[(b << 13) + oidx[(b << 13) + p]] = dl[15];
}

// ---------------- K1: LDS-staged bound-filter KNN + exact select + spatial encoding ----
// grid 1024 = 2 batches x 512 groups of 16 queries; block 256; thread: query=t&15,
// partition=t>>4 scans candidates {part + 16j} of each LDS tile (4 broadcast
// addresses/wave -> conflict-free). Candidate tiles (1024 float4 = 16KB) are
// software-pipelined: next tile's coalesced global loads issue BEFORE scanning the
// current tile, hiding L2 latency under the scan (R12 was latency-bound: the bare
// filter loop left nothing to cover its serial per-thread L2 loads).
// Selection semantics identical to R12 (proven): predicate d <= T_q (exact bound),
// append survivors; scnt counts ALL; overflowed queries (loose T at Morton jumps)
// recomputed exactly by one wave; exact lex-(d2,idx) top-16 -> jax top_k semantics;
// set-determined -> deterministic despite atomics.
__global__ __launch_bounds__(256) void k_knn(const float4* __restrict__ cp4,
                                             const float* __restrict__ tbound,
                                             float* __restrict__ se) {
    __shared__ __align__(16) float4 tile[1024];   // 16 KB
    __shared__ uint2 surv[16][CAP + 1];           // 16.5 KB (+1 pad)
    __shared__ int scnt[16];
    __shared__ float sd[16][17];
    __shared__ int   si[16][17];

    int t = threadIdx.x;
    int b = blockIdx.x >> 9;
    int qbase = (blockIdx.x & 511) * 16;
    int ql = t & 15, part = t >> 4;
    int wv = t >> 6, lane = t & 63;
    const float4* cp = cp4 + ((size_t)b << 13);
    int q = qbase + ql;
    float4 qc = cp[q];
    float T = tbound[(b << 13) + q];

    if (t < 16) scnt[t] = 0;

    // pipeline: load tile 0 into registers
    float4 r0 = cp[t], r1 = cp[t + 256], r2 = cp[t + 512], r3 = cp[t + 768];

    for (int tb = 0; tb < 8192; tb += 1024) {
        __syncthreads();                    // previous scan done (and scnt init on first iter)
        tile[t] = r0; tile[t + 256] = r1; tile[t + 512] = r2; tile[t + 768] = r3;
        if (tb + 1024 < 8192) {             // issue next tile's loads; latency hides under scan
            const float4* nx = cp + tb + 1024;
            r0 = nx[t]; r1 = nx[t + 256]; r2 = nx[t + 512]; r3 = nx[t + 768];
        }
        __syncthreads();
        for (int j = 0; j < 64; j += 4) {
            float4 c0 = tile[part + 16 * j];
            float4 c1 = tile[part + 16 * (j + 1)];
            float4 c2 = tile[part + 16 * (j + 2)];
            float4 c3 = tile[part + 16 * (j + 3)];
            float d0 = dist2(qc, c0), d1 = dist2(qc, c1), d2v = dist2(qc, c2), d3 = dist2(qc, c3);
            bool p0 = d0 <= T, p1 = d1 <= T, p2 = d2v <= T, p3 = d3 <= T;
            if (__any(p0 | p1 | p2 | p3)) {
                int jb = tb + part;
                if (p0) { int pos = atomicAdd(&scnt[ql], 1); if (pos < CAP) surv[ql][pos] = make_uint2(__float_as_uint(d0), (unsigned)(jb + 16 * j)); }
                if (p1) { int pos = atomicAdd(&scnt[ql], 1); if (pos < CAP) surv[ql][pos] = make_uint2(__float_as_uint(d1), (unsigned)(jb + 16 * (j + 1))); }
                if (p2) { int pos = atomicAdd(&scnt[ql], 1); if (pos < CAP) surv[ql][pos] = make_uint2(__float_as_uint(d2v), (unsigned)(jb + 16 * (j + 2))); }
                if (p3) { int pos = atomicAdd(&scnt[ql], 1); if (pos < CAP) surv[ql][pos] = make_uint2(__float_as_uint(d3), (unsigned)(jb + 16 * (j + 3))); }
            }
        }
    }
    __syncthreads();

    // fallback: exact wave-parallel top-16 for overflowed queries (rare; wave-uniform branch)
    for (int q2 = wv; q2 < 16; q2 += 4) {
        if (scnt[q2] > CAP) {
            float4 qc2 = cp[qbase + q2];
            float dl[16]; int il[16];
#pragma unroll
            for (int i = 0; i < 16; ++i) { dl[i] = FLT_MAX; il[i] = 0x7fffffff; }
            for (int i = 0; i < 128; ++i) {       // coalesced: lane + 64*i
                int j = lane + (i << 6);
                float d = dist2(qc2, cp[j]);
                if (d < dl[15] || (d == dl[15] && j < il[15])) ins16_lex(dl, il, d, j);
            }
            // 6-round butterfly: after round r each lane holds top-16 of 2^(r+1) lanes' union
            for (int o = 1; o < 64; o <<= 1) {
                float dd[16]; int ii[16];
#pragma unroll
                for (int i = 0; i < 16; ++i) { dd[i] = __shfl_xor(dl[i], o); ii[i] = __shfl_xor(il[i], o); }
#pragma unroll
                for (int i = 0; i < 16; ++i) {
                    if (dd[i] < dl[15] || (dd[i] == dl[15] && ii[i] < il[15])) ins16_lex(dl, il, dd[i], ii[i]);
                }
            }
            if (lane == 0) {
#pragma unroll
                for (int i = 0; i < 16; ++i) { sd[q2][i] = dl[i]; si[q2][i] = il[i]; }
            }
        }
    }

    // phase C: exact lex top-16 of survivors (one thread per query, non-overflowed only)
    if (t < 16 && scnt[t] <= CAP) {
        int n = scnt[t];
        float dl[16]; int il[16];
#pragma unroll
        for (int i = 0; i < 16; ++i) { dl[i] = FLT_MAX; il[i] = 0x7fffffff; }
        for (int s2 = 0; s2 < n; ++s2) {
            uint2 v = surv[t][s2];
            float d = __uint_as_float(v.x); int id = (int)v.y;
            if (d < dl[15] || (d == dl[15] && id < il[15])) ins16_lex(dl, il, d, id);
        }
#pragma unroll
        for (int i = 0; i < 16; ++i) { sd[t][i] = dl[i]; si[t][i] = il[i]; }
    }
    __syncthreads();

    // epilogue: 256 threads write 256 se rows (one (q,k) slot each)
    {
        int qq = t >> 4, k = t & 15;
        float d2s = sd[qq][k]; int id = si[qq][k];
        float4 qc2 = cp[qbase + qq];
        float4 nb = cp[id];
        float dist = sqrtf(fmaxf(d2s, 1e-12f));
        float* sp = se + ((size_t)(b * NN + qbase + qq) * KK + k) * 10;
        sp[0] = qc2.x; sp[1] = qc2.y; sp[2] = qc2.z;
        sp[3] = nb.x;  sp[4] = nb.y;  sp[5] = nb.z;
        sp[6] = qc2.x - nb.x; sp[7] = qc2.y - nb.y; sp[8] = qc2.z - nb.z;
        sp[9] = dist;
    }
}

// ---------------- K2: mlp1 + shortcut linear + shortcut BN stats ----------------
__global__ __launch_bounds__(128) void k_feat(const float* __restrict__ feat,
                                              const float* __restrict__ Wm1, const float* __restrict__ bm1,
                                              const float* __restrict__ Wsh, const float* __restrict__ bsh,
                                              float* __restrict__ xf, float* __restrict__ short_pre,
                                              double* __restrict__ stats) {
    __shared__ float fl[32][33];
    int t = threadIdx.x;
    int pbase = blockIdx.x * 32;
    float wcol[32];
#pragma unroll
    for (int i = 0; i < 32; ++i) wcol[i] = Wsh[i * C2 + t];
    float wm[32];
    if (t < 32) {
#pragma unroll
        for (int i = 0; i < 32; ++i) wm[i] = Wm1[i * HH + t];
    }
    float bs = bsh[t];
    float bm = (t < 32) ? bm1[t] : 0.f;
    double s = 0.0, s2 = 0.0;

    for (int e = t; e < 1024; e += 128) {
        int p = e >> 5, i = e & 31;
        fl[p][i] = feat[(size_t)(pbase + p) * CIN + i];
    }
    __syncthreads();
    for (int p = 0; p < 32; ++p) {
        float acc = bs;
#pragma unroll
        for (int i = 0; i < 32; ++i) acc += fl[p][i] * wcol[i];
        int gp = pbase + p;
        short_pre[(size_t)gp * C2 + t] = acc;
        s += acc; s2 += (double)acc * acc;
        if (t < 32) {
            float xv = bm;
#pragma unroll
            for (int i = 0; i < 32; ++i) xv += fl[p][i] * wm[i];
            xf[(size_t)gp * HH + t] = xv >= 0.f ? xv : 0.2f * xv;
        }
    }
    atomicAdd(&stats[S_SHORT + t], s);
    atomicAdd(&stats[S_SHORT + C2 + t], s2);
}

// ---------------- K3: lse1+lse2 linear BN stats (LDS-staged) ----------------
__global__ __launch_bounds__(256) void k_lse_stats(const float* __restrict__ se,
                                                   const float* __restrict__ W1, const float* __restrict__ b1,
                                                   const float* __restrict__ W2, const float* __restrict__ b2,
                                                   double* __restrict__ stats) {
    __shared__ float srows[256][10];
    __shared__ double red[4][64][2];
    int t = threadIdx.x;
    int c = t & 63, grp = t >> 6;
    int ch = c & 31; bool second = c >= 32;
    const float* W = second ? W2 : W1;
    float wcol[10];
#pragma unroll
    for (int d = 0; d < 10; ++d) wcol[d] = W[d * HH + ch];
    float bb = second ? b2[ch] : b1[ch];
    double s = 0.0, s2 = 0.0;
    int rbase = blockIdx.x * 512;

    for (int tile = 0; tile < 2; ++tile) {
        __syncthreads();
        const float* src = se + (size_t)(rbase + tile * 256) * 10;
        for (int e = t; e < 2560; e += 256) srows[e / 10][e % 10] = src[e];
        __syncthreads();
        int r0 = grp * 64;
        for (int r = r0; r < r0 + 64; ++r) {
            float acc = bb;
#pragma unroll
            for (int d = 0; d < 10; ++d) acc += srows[r][d] * wcol[d];
            s += acc; s2 += (double)acc * acc;
        }
    }
    red[grp][c][0] = s; red[grp][c][1] = s2;
    __syncthreads();
    if (grp == 0) {
        for (int g = 1; g < 4; ++g) { s += red[g][c][0]; s2 += red[g][c][1]; }
        int base = second ? S_LSE2 : S_LSE1;
        atomicAdd(&stats[base + ch], s);
        atomicAdd(&stats[base + 32 + ch], s2);
    }
}

// BN scale/shift from raw stats (computed redundantly in consumer prologues)
DEV float2 fin_pair(const double* stats, int sbase, int ch, int nch, double M,
                    const float* g, const float* be) {
    double mean = stats[sbase + ch] / M;
    double var = stats[sbase + nch + ch] / M - mean * mean;
    double scd = (double)g[ch] / sqrt(var + (double)EPSF);
    return make_float2((float)scd, (float)((double)be[ch] - mean * scd));
}

// ---------------- K5/K7: fused LocSE + attentive pooling + MLP ----------------
template <int OUTC, bool SECOND>
__global__ __launch_bounds__(256) void k_att(const float* __restrict__ se,
                                             const float* __restrict__ featsrc,
                                             const float* __restrict__ Wlse, const float* __restrict__ blse,
                                             const float* __restrict__ Wlin,
                                             const float* __restrict__ Wmlp, const float* __restrict__ bmlp,
                                             double* __restrict__ stats, int lse_sbase, int feat_sbase, int stat_base,
                                             const float* __restrict__ g_lse, const float* __restrict__ be_lse,
                                             const float* __restrict__ g_f, const float* __restrict__ be_f,
                                             float* __restrict__ preout) {
    __shared__ __align__(16) float wlt[64][68];
    __shared__ float wm[64][OUTC];
    __shared__ __align__(16) float x1[4][16][40];
    __shared__ float fv[4][32];
    __shared__ float p1b[4][64];
    __shared__ double red[4][OUTC][2];

    int t = threadIdx.x, w = t >> 6, c = t & 63;
    int ch = c & 31, half = c >> 5;
    for (int e = t; e < 4096; e += 256) wlt[e & 63][e >> 6] = Wlin[e];
    for (int e = t; e < 64 * OUTC; e += 256) wm[e / OUTC][e % OUTC] = Wmlp[e];

    float wf[10]; float bf;
    {
        float2 p = fin_pair(stats, lse_sbase, ch, 32, (double)BNKROWS, g_lse, be_lse);
#pragma unroll
        for (int d = 0; d < 10; ++d) wf[d] = Wlse[d * 32 + ch] * p.x;
        bf = blse[ch] * p.x + p.y;
    }
    float fa = 1.f, fb = 0.f;
    if (SECOND && c >= 32) {
        float2 p = fin_pair(stats, feat_sbase, ch, 32, (double)BNTOT, g_f, be_f);
        fa = p.x; fb = p.y;
    }
    double s = 0.0, s2 = 0.0;
    __syncthreads();

    for (int i = 0; i < 4; ++i) {
        int p = blockIdx.x * 16 + w * 4 + i;

        int kbase = half * 8;
        const float* sp = se + (size_t)p * (KK * 10) + kbase * 10;
        float myv[8];
#pragma unroll
        for (int kk = 0; kk < 8; ++kk) {
            float acc = bf;
#pragma unroll
            for (int d = 0; d < 10; ++d) acc += sp[kk * 10 + d] * wf[d];
            myv[kk] = fmaxf(acc, 0.f);
        }
#pragma unroll
        for (int kk = 0; kk < 8; ++kk) x1[w][kbase + kk][ch] = myv[kk];

        float xv = 0.f;
        if (c >= 32) {
            xv = featsrc[(size_t)p * 32 + ch];
            if (SECOND) xv = fmaxf(xv * fa + fb, 0.f);
            fv[w][ch] = xv;
        }

        float col[16];
        if (c < 32) {
#pragma unroll
            for (int kk = 0; kk < 8; ++kk) col[kk] = myv[kk];
#pragma unroll
            for (int kk = 0; kk < 8; ++kk) col[8 + kk] = x1[w][8 + kk][ch];
        } else {
#pragma unroll
            for (int k = 0; k < 16; ++k) col[k] = xv;
        }

        float cst = 0.f;
#pragma unroll
        for (int dg = 8; dg < 16; ++dg) {
            float4 wv = *(const float4*)&wlt[c][dg * 4];
            float4 xvv = *(const float4*)&fv[w][(dg - 8) * 4];
            cst += xvv.x * wv.x + xvv.y * wv.y + xvv.z * wv.z + xvv.w * wv.w;
        }
        float scv[16];
#pragma unroll
        for (int k = 0; k < 16; ++k) scv[k] = cst;
        for (int dg = 0; dg < 8; ++dg) {
            float4 wv = *(const float4*)&wlt[c][dg * 4];
#pragma unroll
            for (int k = 0; k < 16; ++k) {
                float4 xvv = *(const float4*)&x1[w][k][dg * 4];
                scv[k] += xvv.x * wv.x + xvv.y * wv.y + xvv.z * wv.z + xvv.w * wv.w;
            }
        }
        float m = scv[0];
#pragma unroll
        for (int k = 1; k < 16; ++k) m = fmaxf(m, scv[k]);
        float sum = 0.f, p1 = 0.f;
#pragma unroll
        for (int k = 0; k < 16; ++k) { float e = __expf(scv[k] - m); sum += e; p1 += e * col[k]; }
        p1 /= sum;
        p1b[w][c] = p1;

        if (c < OUTC) {
            float acc = bmlp[c];
#pragma unroll
            for (int d = 0; d < 64; ++d) acc += p1b[w][d] * wm[d][c];
            preout[(size_t)p * OUTC + c] = acc;
            s += acc; s2 += (double)acc * acc;
        }
    }
    if (c < OUTC) { red[w][c][0] = s; red[w][c][1] = s2; }
    __syncthreads();
    if (t < OUTC) {
        double ts = red[0][t][0], ts2 = red[0][t][1];
        for (int g = 1; g < 4; ++g) { ts += red[g][t][0]; ts2 += red[g][t][1]; }
        atomicAdd(&stats[stat_base + t], ts);
        atomicAdd(&stats[stat_base + OUTC + t], ts2);
    }
}

// ---------------- K9: final mlp2 + shortcut BN + residual leaky + transposed write ----
__global__ __launch_bounds__(256) void k_out(const float* __restrict__ pre2,
                                             const float* __restrict__ short_pre,
                                             const float* __restrict__ W2, const float* __restrict__ b2,
                                             const double* __restrict__ stats,
                                             const float* __restrict__ g_a2, const float* __restrict__ be_a2,
                                             const float* __restrict__ g_s, const float* __restrict__ be_s,
                                             float* __restrict__ out) {
    __shared__ __align__(16) float w2[64][128];
    __shared__ float sc2[64], sh2[64], scs[128], shs[128], bb[128];
    int t = threadIdx.x;
    int pl = t & 31, seg = t >> 5;
    for (int e = t; e < 8192; e += 256) w2[e >> 7][e & 127] = W2[e];
    if (t < 64) { float2 p = fin_pair(stats, S_ATT2, t, 64, (double)BNTOT, g_a2, be_a2); sc2[t] = p.x; sh2[t] = p.y; }
    if (t >= 64 && t < 192) { int ch = t - 64; float2 p = fin_pair(stats, S_SHORT, ch, 128, (double)BNTOT, g_s, be_s); scs[ch] = p.x; shs[ch] = p.y; }
    if (t < 128) bb[t] = b2[t];
    __syncthreads();

    int p = blockIdx.x * 32 + pl;
    int b = p >> 13, n = p & 8191;
    const float* pr = pre2 + (size_t)p * 64;
    float xa[64];
#pragma unroll
    for (int c = 0; c < 64; c += 4) {
        float4 v = *(const float4*)&pr[c];
        xa[c + 0] = fmaxf(v.x * sc2[c + 0] + sh2[c + 0], 0.f);
        xa[c + 1] = fmaxf(v.y * sc2[c + 1] + sh2[c + 1], 0.f);
        xa[c + 2] = fmaxf(v.z * sc2[c + 2] + sh2[c + 2], 0.f);
        xa[c + 3] = fmaxf(v.w * sc2[c + 3] + sh2[c + 3], 0.f);
    }
    const float* shp = short_pre + (size_t)p * 128;
    int obase = seg * 16;
    for (int o = obase; o < obase + 16; o += 4) {
        float a0 = bb[o], a1 = bb[o + 1], a2 = bb[o + 2], a3 = bb[o + 3];
#pragma unroll
        for (int cc = 0; cc < 64; ++cc) {
            float4 wv = *(const float4*)&w2[cc][o];
            float x = xa[cc];
            a0 += x * wv.x; a1 += x * wv.y; a2 += x * wv.z; a3 += x * wv.w;
        }
        float4 sv = *(const float4*)&shp[o];
        float r0 = a0 + (sv.x * scs[o] + shs[o]);
        float r1 = a1 + (sv.y * scs[o + 1] + shs[o + 1]);
        float r2 = a2 + (sv.z * scs[o + 2] + shs[o + 2]);
        float r3 = a3 + (sv.w * scs[o + 3] + shs[o + 3]);
        out[((size_t)(b * C2 + o + 0)) * NN + n] = r0 >= 0.f ? r0 : 0.01f * r0;
        out[((size_t)(b * C2 + o + 1)) * NN + n] = r1 >= 0.f ? r1 : 0.01f * r1;
        out[((size_t)(b * C2 + o + 2)) * NN + n] = r2 >= 0.f ? r2 : 0.01f * r2;
        out[((size_t)(b * C2 + o + 3)) * NN + n] = r3 >= 0.f ? r3 : 0.01f * r3;
    }
}

extern "C" void kernel_launch(void* const* d_in, const int* in_sizes, int n_in,
                              void* d_out, int out_size, void* d_ws, size_t ws_size,
                              hipStream_t stream) {
    const float* coords    = (const float*)d_in[0];
    const float* features  = (const float*)d_in[1];
    const float* W_mlp1    = (const float*)d_in[2];
    const float* b_mlp1    = (const float*)d_in[3];
    const float* W_lse1    = (const float*)d_in[4];
    const float* b_lse1    = (const float*)d_in[5];
    const float* g_lse1    = (const float*)d_in[6];
    const float* be_lse1   = (const float*)d_in[7];
    const float* W_att1_lin= (const float*)d_in[8];
    const float* W_att1_mlp= (const float*)d_in[9];
    const float* b_att1_mlp= (const float*)d_in[10];
    const float* g_att1    = (const float*)d_in[11];
    const float* be_att1   = (const float*)d_in[12];
    const float* W_lse2    = (const float*)d_in[13];
    const float* b_lse2    = (const float*)d_in[14];
    const float* g_lse2    = (const float*)d_in[15];
    const float* be_lse2   = (const float*)d_in[16];
    const float* W_att2_lin= (const float*)d_in[17];
    const float* W_att2_mlp= (const float*)d_in[18];
    const float* b_att2_mlp= (const float*)d_in[19];
    const float* g_att2    = (const float*)d_in[20];
    const float* be_att2   = (const float*)d_in[21];
    const float* W_mlp2    = (const float*)d_in[22];
    const float* b_mlp2    = (const float*)d_in[23];
    const float* W_short   = (const float*)d_in[24];
    const float* b_short   = (const float*)d_in[25];
    const float* g_short   = (const float*)d_in[26];
    const float* be_short  = (const float*)d_in[27];

    float* ws = (float*)d_ws;
    float4* cp4      = (float4*)(ws + OFF_CP4);
    float* se        = ws + OFF_SE;
    float* xf        = ws + OFF_XF;
    float* short_pre = ws + OFF_SHORT;
    float* pre1      = ws + OFF_PRE1;
    float* pre2      = ws + OFF_PRE2;
    double* stats    = (double*)(ws + OFF_STATS);
    int* counts      = (int*)(ws + OFF_COUNTS);
    float* tbound    = ws + OFF_TB;
    int* code        = (int*)(ws + OFF_CODE);
    float4* cps      = (float4*)(ws + OFF_CPS);
    int* oidxArr     = (int*)(ws + OFF_OIDX);
    float* out       = (float*)d_out;

    // zero stats (576 doubles) + counts (8192 ints), contiguous
    hipMemsetAsync(stats, 0, S_TOTAL * 8 + 2 * NCELL * 4, stream);

    k_prep<<<BNTOT / 256, 256, 0, stream>>>(coords, cp4, code, counts);
    k_scan<<<1, 256, 0, stream>>>(counts);
    k_scatter<<<BNTOT / 256, 256, 0, stream>>>(cp4, code, counts, cps, oidxArr);
    k_seed<<<BNTOT / 256, 256, 0, stream>>>(cps, oidxArr, tbound);
    k_knn<<<1024, 256, 0, stream>>>(cp4, tbound, se);
    k_feat<<<512, 128, 0, stream>>>(features, W_mlp1, b_mlp1, W_short, b_short,
                                    xf, short_pre, stats);
    k_lse_stats<<<512, 256, 0, stream>>>(se, W_lse1, b_lse1, W_lse2, b_lse2, stats);
    k_att<32, false><<<1024, 256, 0, stream>>>(se, xf, W_lse1, b_lse1, W_att1_lin,
                                               W_att1_mlp, b_att1_mlp, stats,
                                               S_LSE1, 0, S_ATT1,
                                               g_lse1, be_lse1, nullptr, nullptr, pre1);
    k_att<64, true><<<1024, 256, 0, stream>>>(se, pre1, W_lse2, b_lse2, W_att2_lin,
                                              W_att2_mlp, b_att2_mlp, stats,
                                              S_LSE2, S_ATT1, S_ATT2,
                                              g_lse2, be_lse2, g_att1, be_att1, pre2);
    k_out<<<BNTOT / 32, 256, 0, stream>>>(pre2, short_pre, W_mlp2, b_mlp2, stats,
                                          g_att2, be_att2, g_short, be_short, out);
}

// Round 14
// 436.909 us; speedup vs baseline: 1.3870x; 1.3551x over previous
//
#include <hip/hip_runtime.h>
#include <cfloat>
#include <cmath>

#define DEV __device__ __forceinline__

constexpr int BB = 2, NN = 8192, KK = 16, CIN = 32, HH = 32, CO = 64, C2 = 128;
constexpr int BNTOT = BB * NN;        // 16384
constexpr int BNKROWS = BB * NN * KK; // 262144
constexpr float EPSF = 1e-6f;
constexpr int NCELL = 4096;           // 16^3 morton cells
constexpr int CAP = 128;              // survivor capacity per query

// stats indices (doubles): [sum.., sumsq..] per group
constexpr int S_LSE1 = 0, S_LSE2 = 64, S_ATT1 = 128, S_ATT2 = 192, S_SHORT = 320, S_TOTAL = 576;

// workspace layout (in floats)
constexpr size_t OFF_CP4   = 0;                                  // orig-order (x,y,z,sq): 16384*4
constexpr size_t OFF_SE    = OFF_CP4 + (size_t)BNTOT * 4;        // se (B,N,K,10)
constexpr size_t OFF_XF    = OFF_SE + (size_t)BNKROWS * 10;      // mlp1 out (B,N,32)
constexpr size_t OFF_SHORT = OFF_XF + (size_t)BNTOT * HH;        // shortcut pre-BN (B,N,128)
constexpr size_t OFF_PRE1  = OFF_SHORT + (size_t)BNTOT * C2;     // att1 pre-BN (B,N,32)
constexpr size_t OFF_PRE2  = OFF_PRE1 + (size_t)BNTOT * HH;      // att2 pre-BN (B,N,64)
constexpr size_t OFF_STATS = OFF_PRE2 + (size_t)BNTOT * CO;      // doubles x576 (even -> 8B aligned)
constexpr size_t OFF_COUNTS= OFF_STATS + 2 * S_TOTAL;            // int[2][4096]
constexpr size_t OFF_TB    = OFF_COUNTS + 2 * NCELL;             // float[16384] T_q bounds
// sort scratch overlaid in SHORT region (dead until k_feat, which runs after k_knn)
constexpr size_t OFF_CODE  = OFF_SHORT;                          // int[16384]
constexpr size_t OFF_CPS   = OFF_CODE + 16384;                   // float4[2][8192] + 4 pad
constexpr size_t OFF_OIDX  = OFF_CPS + (size_t)BNTOT * 4 + 16;   // int[2][8192]

DEV unsigned spr3(unsigned v) {
    return (v & 1u) | ((v & 2u) << 2) | ((v & 4u) << 4) | ((v & 8u) << 6);
}

// ---------------- K0: pack (x,y,z,sq) + morton cell + counts ----------------
__global__ __launch_bounds__(256) void k_prep(const float* __restrict__ coords,
                                              float4* __restrict__ cp4,
                                              int* __restrict__ code, int* __restrict__ counts) {
#pragma clang fp contract(off)
    int i = blockIdx.x * 256 + threadIdx.x;
    if (i >= BNTOT) return;
    float x = coords[3 * i], y = coords[3 * i + 1], z = coords[3 * i + 2];
    float sq = (x * x + y * y) + z * z;   // match numpy sum order, no FMA
    cp4[i] = make_float4(x, y, z, sq);
    const float inv = 16.f / 8.8f;
    int ix = min(15, max(0, (int)floorf((x + 4.4f) * inv)));
    int iy = min(15, max(0, (int)floorf((y + 4.4f) * inv)));
    int iz = min(15, max(0, (int)floorf((z + 4.4f) * inv)));
    unsigned m = spr3(ix) | (spr3(iy) << 1) | (spr3(iz) << 2);
    code[i] = (int)m;
    atomicAdd(&counts[((i >> 13) << 12) + m], 1);
}

// ---------------- K0b: exclusive prefix scan of counts (per batch) ----------------
__global__ __launch_bounds__(256) void k_scan(int* __restrict__ counts) {
    __shared__ int lds[256];
    int t = threadIdx.x;
    for (int b = 0; b < 2; ++b) {
        int base = b * NCELL;
        int v[16]; int s = 0;
#pragma unroll
        for (int k = 0; k < 16; ++k) { int tmp = counts[base + t * 16 + k]; v[k] = s; s += tmp; }
        lds[t] = s;
        __syncthreads();
        for (int o = 1; o < 256; o <<= 1) {
            int u = (t >= o) ? lds[t - o] : 0;
            __syncthreads();
            lds[t] += u;
            __syncthreads();
        }
        int off = lds[t] - s;   // exclusive
#pragma unroll
        for (int k = 0; k < 16; ++k) counts[base + t * 16 + k] = off + v[k];
        __syncthreads();
    }
}

// ---------------- K0c: scatter into sorted order ----------------
__global__ __launch_bounds__(256) void k_scatter(const float4* __restrict__ cp4,
                                                 const int* __restrict__ code,
                                                 int* __restrict__ cursor,
                                                 float4* __restrict__ cps, int* __restrict__ oidx) {
    int i = blockIdx.x * 256 + threadIdx.x;
    if (i >= BNTOT) return;
    int b = i >> 13, n = i & 8191;
    int c = code[i];
    int pos = atomicAdd(&cursor[(b << 12) + c], 1);
    cps[(b << 13) + pos] = cp4[i];
    oidx[(b << 13) + pos] = n;
}

DEV float dist2(float4 qc, float4 c) {
#pragma clang fp contract(off)
    float dot = (qc.x * c.x + qc.y * c.y) + qc.z * c.z;
    return (qc.w + c.w) - 2.0f * dot;   // exact jax/np expansion formula
}

// value-only sorted insert (16-deep): keeps 16 smallest values
DEV void insv16(float (&dl)[16], float d) {
    float dk = d;
#pragma unroll
    for (int r = 0; r < 16; ++r) {
        bool c = dk < dl[r];
        float td = dl[r];
        dl[r] = c ? dk : dl[r];
        dk = c ? td : dk;
    }
}

// lexicographic (d, idx) sorted insert
DEV void ins16_lex(float (&dl)[16], int (&il)[16], float d, int id) {
    float dk = d; int jk = id;
#pragma unroll
    for (int r = 0; r < 16; ++r) {
        bool c = (dk < dl[r]) || (dk == dl[r] && jk < il[r]);
        float td = dl[r]; int ti = il[r];
        dl[r] = c ? dk : dl[r]; il[r] = c ? jk : il[r];
        dk = c ? td : dk; jk = c ? ti : jk;
    }
}

// ---------------- K0d: per-query threshold bound from 256 Morton-window neighbors ----
// T_q = 16th-smallest exact d2 among the query's 256 sorted-order neighbors.
// Subset 16th order-stat >= global 16th order-stat -> EXACT upper bound, no margin.
// (Bound can be LOOSE where the Morton curve jumps; k_knn's refine handles that.)
__global__ __launch_bounds__(256) void k_seed(const float4* __restrict__ cps,
                                              const int* __restrict__ oidx,
                                              float* __restrict__ tbound) {
    int g = blockIdx.x * 256 + threadIdx.x;
    int b = g >> 13, p = g & 8191;
    const float4* cb_ = cps + ((size_t)b << 13);
    float4 qc = cb_[p];
    int s = p - 128;
    s = s < 0 ? 0 : (s > NN - 256 ? NN - 256 : s);
    float dl[16];
#pragma unroll
    for (int i = 0; i < 16; ++i) dl[i] = FLT_MAX;
    for (int j = 0; j < 256; j += 4) {
        float4 c0 = cb_[s + j], c1 = cb_[s + j + 1], c2 = cb_[s + j + 2], c3 = cb_[s + j + 3];
        float d0 = dist2(qc, c0), d1 = dist2(qc, c1), d2v = dist2(qc, c2), d3 = dist2(qc, c3);
        if (d0 < dl[15]) insv16(dl, d0);
        if (d1 < dl[15]) insv16(dl, d1);
        if (d2v < dl[15]) insv16(dl, d2v);
        if (d3 < dl[15]) insv16(dl, d3);
    }
    tbound[(b << 13) + oidx[(b << 13) + p]] = dl[15];
}

// ---------------- K1: LDS-staged bound-filter KNN + exact select + spatial encoding ----
// grid 1024 = 2 batches x 512 groups of 16 queries; block 256; thread: query=t&15,
// partition=t>>4 scans candidates {part + 16j} of each LDS tile.
// Main scan: predicate d <= T_q (exact precomputed bound) -> append survivor to LDS.
// Overflow (scnt > CAP, loose T at Morton jumps — R13's straggler: serial per-wave
// fallback cost ~38K cyc/query) is now handled by REFINE: T2 = 16th-smallest among
// the kept CAP survivors (they are real points -> T2 >= d16 exactly), then a
// block-cooperative coalesced rescan with T2 (expected count ~M/8 <= CAP). If the
// rescan still overflows (ultra-rare), the serial exact scan runs. All paths give
// the exact lex-(d2,idx) top-16 == jax top_k; outcome set-determined -> deterministic.
__global__ __launch_bounds__(256) void k_knn(const float4* __restrict__ cp4,
                                             const float* __restrict__ tbound,
                                             float* __restrict__ se) {
    __shared__ __align__(16) float4 tile[1024];   // 16 KB
    __shared__ uint2 surv[16][CAP + 1];           // 16.5 KB (+1 pad)
    __shared__ int scnt[16];
    __shared__ float sd[16][17];
    __shared__ int   si[16][17];
    __shared__ int nof;
    __shared__ float t2s;

    int t = threadIdx.x;
    int b = blockIdx.x >> 9;
    int qbase = (blockIdx.x & 511) * 16;
    int ql = t & 15, part = t >> 4;
    int wv = t >> 6, lane = t & 63;
    const float4* cp = cp4 + ((size_t)b << 13);
    int q = qbase + ql;
    float4 qc = cp[q];
    float T = tbound[(b << 13) + q];

    if (t < 16) scnt[t] = 0;
    if (t == 16) nof = 0;

    // pipeline: load tile 0 into registers
    float4 r0 = cp[t], r1 = cp[t + 256], r2 = cp[t + 512], r3 = cp[t + 768];

    for (int tb = 0; tb < 8192; tb += 1024) {
        __syncthreads();                    // previous scan done (and scnt/nof init on first iter)
        tile[t] = r0; tile[t + 256] = r1; tile[t + 512] = r2; tile[t + 768] = r3;
        if (tb + 1024 < 8192) {             // issue next tile's loads; latency hides under scan
            const float4* nx = cp + tb + 1024;
            r0 = nx[t]; r1 = nx[t + 256]; r2 = nx[t + 512]; r3 = nx[t + 768];
        }
        __syncthreads();
        for (int j = 0; j < 64; j += 4) {
            float4 c0 = tile[part + 16 * j];
            float4 c1 = tile[part + 16 * (j + 1)];
            float4 c2 = tile[part + 16 * (j + 2)];
            float4 c3 = tile[part + 16 * (j + 3)];
            float d0 = dist2(qc, c0), d1 = dist2(qc, c1), d2v = dist2(qc, c2), d3 = dist2(qc, c3);
            bool p0 = d0 <= T, p1 = d1 <= T, p2 = d2v <= T, p3 = d3 <= T;
            if (__any(p0 | p1 | p2 | p3)) {
                int jb = tb + part;
                if (p0) { int pos = atomicAdd(&scnt[ql], 1); if (pos < CAP) surv[ql][pos] = make_uint2(__float_as_uint(d0), (unsigned)(jb + 16 * j)); }
                if (p1) { int pos = atomicAdd(&scnt[ql], 1); if (pos < CAP) surv[ql][pos] = make_uint2(__float_as_uint(d1), (unsigned)(jb + 16 * (j + 1))); }
                if (p2) { int pos = atomicAdd(&scnt[ql], 1); if (pos < CAP) surv[ql][pos] = make_uint2(__float_as_uint(d2v), (unsigned)(jb + 16 * (j + 2))); }
                if (p3) { int pos = atomicAdd(&scnt[ql], 1); if (pos < CAP) surv[ql][pos] = make_uint2(__float_as_uint(d3), (unsigned)(jb + 16 * (j + 3))); }
            }
        }
    }
    __syncthreads();

    // ---- refine pass: overflowed queries get a tighter exact bound + coalesced rescan ----
    if (t < 16 && scnt[t] > CAP) atomicAdd(&nof, 1);
    __syncthreads();
    if (nof) {
        for (int q2 = 0; q2 < 16; ++q2) {
            int n0 = scnt[q2];                  // uniform (post-barrier)
            __syncthreads();                    // all read n0 before any reset
            if (n0 <= CAP) continue;
            if (t == 0) {                       // T2 = 16th among kept survivors (real points -> exact bound)
                float dl[16];
#pragma unroll
                for (int i = 0; i < 16; ++i) dl[i] = FLT_MAX;
                for (int s2 = 0; s2 < CAP; ++s2) {
                    float d = __uint_as_float(surv[q2][s2].x);
                    if (d < dl[15]) insv16(dl, d);
                }
                t2s = dl[15];
                scnt[q2] = 0;
            }
            __syncthreads();
            float T2 = t2s;
            float4 qc2 = cp[qbase + q2];
            int jb = t * 32;                    // block-cooperative coalesced rescan
            for (int j = jb; j < jb + 32; j += 4) {
                float4 c0 = cp[j], c1 = cp[j + 1], c2 = cp[j + 2], c3 = cp[j + 3];
                float d0 = dist2(qc2, c0), d1 = dist2(qc2, c1), d2v = dist2(qc2, c2), d3 = dist2(qc2, c3);
                if (d0 <= T2) { int pos = atomicAdd(&scnt[q2], 1); if (pos < CAP) surv[q2][pos] = make_uint2(__float_as_uint(d0), (unsigned)j); }
                if (d1 <= T2) { int pos = atomicAdd(&scnt[q2], 1); if (pos < CAP) surv[q2][pos] = make_uint2(__float_as_uint(d1), (unsigned)(j + 1)); }
                if (d2v <= T2) { int pos = atomicAdd(&scnt[q2], 1); if (pos < CAP) surv[q2][pos] = make_uint2(__float_as_uint(d2v), (unsigned)(j + 2)); }
                if (d3 <= T2) { int pos = atomicAdd(&scnt[q2], 1); if (pos < CAP) surv[q2][pos] = make_uint2(__float_as_uint(d3), (unsigned)(j + 3)); }
            }
            __syncthreads();
        }
    }

    // last-resort: exact wave-parallel top-16 for still-overflowed queries (ultra-rare)
    for (int q2 = wv; q2 < 16; q2 += 4) {
        if (scnt[q2] > CAP) {
            float4 qc2 = cp[qbase + q2];
            float dl[16]; int il[16];
#pragma unroll
            for (int i = 0; i < 16; ++i) { dl[i] = FLT_MAX; il[i] = 0x7fffffff; }
            for (int i = 0; i < 128; ++i) {       // coalesced: lane + 64*i
                int j = lane + (i << 6);
                float d = dist2(qc2, cp[j]);
                if (d < dl[15] || (d == dl[15] && j < il[15])) ins16_lex(dl, il, d, j);
            }
            for (int o = 1; o < 64; o <<= 1) {    // butterfly union-merge
                float dd[16]; int ii[16];
#pragma unroll
                for (int i = 0; i < 16; ++i) { dd[i] = __shfl_xor(dl[i], o); ii[i] = __shfl_xor(il[i], o); }
#pragma unroll
                for (int i = 0; i < 16; ++i) {
                    if (dd[i] < dl[15] || (dd[i] == dl[15] && ii[i] < il[15])) ins16_lex(dl, il, dd[i], ii[i]);
                }
            }
            if (lane == 0) {
#pragma unroll
                for (int i = 0; i < 16; ++i) { sd[q2][i] = dl[i]; si[q2][i] = il[i]; }
            }
        }
    }

    // phase C: exact lex top-16 of survivors (one thread per query, non-overflowed only)
    if (t < 16 && scnt[t] <= CAP) {
        int n = scnt[t];
        float dl[16]; int il[16];
#pragma unroll
        for (int i = 0; i < 16; ++i) { dl[i] = FLT_MAX; il[i] = 0x7fffffff; }
        for (int s2 = 0; s2 < n; ++s2) {
            uint2 v = surv[t][s2];
            float d = __uint_as_float(v.x); int id = (int)v.y;
            if (d < dl[15] || (d == dl[15] && id < il[15])) ins16_lex(dl, il, d, id);
        }
#pragma unroll
        for (int i = 0; i < 16; ++i) { sd[t][i] = dl[i]; si[t][i] = il[i]; }
    }
    __syncthreads();

    // epilogue: 256 threads write 256 se rows (one (q,k) slot each)
    {
        int qq = t >> 4, k = t & 15;
        float d2s = sd[qq][k]; int id = si[qq][k];
        float4 qc2 = cp[qbase + qq];
        float4 nb = cp[id];
        float dist = sqrtf(fmaxf(d2s, 1e-12f));
        float* sp = se + ((size_t)(b * NN + qbase + qq) * KK + k) * 10;
        sp[0] = qc2.x; sp[1] = qc2.y; sp[2] = qc2.z;
        sp[3] = nb.x;  sp[4] = nb.y;  sp[5] = nb.z;
        sp[6] = qc2.x - nb.x; sp[7] = qc2.y - nb.y; sp[8] = qc2.z - nb.z;
        sp[9] = dist;
    }
}

// ---------------- K2: mlp1 + shortcut linear + shortcut BN stats ----------------
__global__ __launch_bounds__(128) void k_feat(const float* __restrict__ feat,
                                              const float* __restrict__ Wm1, const float* __restrict__ bm1,
                                              const float* __restrict__ Wsh, const float* __restrict__ bsh,
                                              float* __restrict__ xf, float* __restrict__ short_pre,
                                              double* __restrict__ stats) {
    __shared__ float fl[32][33];
    int t = threadIdx.x;
    int pbase = blockIdx.x * 32;
    float wcol[32];
#pragma unroll
    for (int i = 0; i < 32; ++i) wcol[i] = Wsh[i * C2 + t];
    float wm[32];
    if (t < 32) {
#pragma unroll
        for (int i = 0; i < 32; ++i) wm[i] = Wm1[i * HH + t];
    }
    float bs = bsh[t];
    float bm = (t < 32) ? bm1[t] : 0.f;
    double s = 0.0, s2 = 0.0;

    for (int e = t; e < 1024; e += 128) {
        int p = e >> 5, i = e & 31;
        fl[p][i] = feat[(size_t)(pbase + p) * CIN + i];
    }
    __syncthreads();
    for (int p = 0; p < 32; ++p) {
        float acc = bs;
#pragma unroll
        for (int i = 0; i < 32; ++i) acc += fl[p][i] * wcol[i];
        int gp = pbase + p;
        short_pre[(size_t)gp * C2 + t] = acc;
        s += acc; s2 += (double)acc * acc;
        if (t < 32) {
            float xv = bm;
#pragma unroll
            for (int i = 0; i < 32; ++i) xv += fl[p][i] * wm[i];
            xf[(size_t)gp * HH + t] = xv >= 0.f ? xv : 0.2f * xv;
        }
    }
    atomicAdd(&stats[S_SHORT + t], s);
    atomicAdd(&stats[S_SHORT + C2 + t], s2);
}

// ---------------- K3: lse1+lse2 linear BN stats (LDS-staged) ----------------
__global__ __launch_bounds__(256) void k_lse_stats(const float* __restrict__ se,
                                                   const float* __restrict__ W1, const float* __restrict__ b1,
                                                   const float* __restrict__ W2, const float* __restrict__ b2,
                                                   double* __restrict__ stats) {
    __shared__ float srows[256][10];
    __shared__ double red[4][64][2];
    int t = threadIdx.x;
    int c = t & 63, grp = t >> 6;
    int ch = c & 31; bool second = c >= 32;
    const float* W = second ? W2 : W1;
    float wcol[10];
#pragma unroll
    for (int d = 0; d < 10; ++d) wcol[d] = W[d * HH + ch];
    float bb = second ? b2[ch] : b1[ch];
    double s = 0.0, s2 = 0.0;
    int rbase = blockIdx.x * 512;

    for (int tile = 0; tile < 2; ++tile) {
        __syncthreads();
        const float* src = se + (size_t)(rbase + tile * 256) * 10;
        for (int e = t; e < 2560; e += 256) srows[e / 10][e % 10] = src[e];
        __syncthreads();
        int r0 = grp * 64;
        for (int r = r0; r < r0 + 64; ++r) {
            float acc = bb;
#pragma unroll
            for (int d = 0; d < 10; ++d) acc += srows[r][d] * wcol[d];
            s += acc; s2 += (double)acc * acc;
        }
    }
    red[grp][c][0] = s; red[grp][c][1] = s2;
    __syncthreads();
    if (grp == 0) {
        for (int g = 1; g < 4; ++g) { s += red[g][c][0]; s2 += red[g][c][1]; }
        int base = second ? S_LSE2 : S_LSE1;
        atomicAdd(&stats[base + ch], s);
        atomicAdd(&stats[base + 32 + ch], s2);
    }
}

// BN scale/shift from raw stats (computed redundantly in consumer prologues)
DEV float2 fin_pair(const double* stats, int sbase, int ch, int nch, double M,
                    const float* g, const float* be) {
    double mean = stats[sbase + ch] / M;
    double var = stats[sbase + nch + ch] / M - mean * mean;
    double scd = (double)g[ch] / sqrt(var + (double)EPSF);
    return make_float2((float)scd, (float)((double)be[ch] - mean * scd));
}

// ---------------- K5/K7: fused LocSE + attentive pooling + MLP ----------------
template <int OUTC, bool SECOND>
__global__ __launch_bounds__(256) void k_att(const float* __restrict__ se,
                                             const float* __restrict__ featsrc,
                                             const float* __restrict__ Wlse, const float* __restrict__ blse,
                                             const float* __restrict__ Wlin,
                                             const float* __restrict__ Wmlp, const float* __restrict__ bmlp,
                                             double* __restrict__ stats, int lse_sbase, int feat_sbase, int stat_base,
                                             const float* __restrict__ g_lse, const float* __restrict__ be_lse,
                                             const float* __restrict__ g_f, const float* __restrict__ be_f,
                                             float* __restrict__ preout) {
    __shared__ __align__(16) float wlt[64][68];
    __shared__ float wm[64][OUTC];
    __shared__ __align__(16) float x1[4][16][40];
    __shared__ float fv[4][32];
    __shared__ float p1b[4][64];
    __shared__ double red[4][OUTC][2];

    int t = threadIdx.x, w = t >> 6, c = t & 63;
    int ch = c & 31, half = c >> 5;
    for (int e = t; e < 4096; e += 256) wlt[e & 63][e >> 6] = Wlin[e];
    for (int e = t; e < 64 * OUTC; e += 256) wm[e / OUTC][e % OUTC] = Wmlp[e];

    float wf[10]; float bf;
    {
        float2 p = fin_pair(stats, lse_sbase, ch, 32, (double)BNKROWS, g_lse, be_lse);
#pragma unroll
        for (int d = 0; d < 10; ++d) wf[d] = Wlse[d * 32 + ch] * p.x;
        bf = blse[ch] * p.x + p.y;
    }
    float fa = 1.f, fb = 0.f;
    if (SECOND && c >= 32) {
        float2 p = fin_pair(stats, feat_sbase, ch, 32, (double)BNTOT, g_f, be_f);
        fa = p.x; fb = p.y;
    }
    double s = 0.0, s2 = 0.0;
    __syncthreads();

    for (int i = 0; i < 4; ++i) {
        int p = blockIdx.x * 16 + w * 4 + i;

        int kbase = half * 8;
        const float* sp = se + (size_t)p * (KK * 10) + kbase * 10;
        float myv[8];
#pragma unroll
        for (int kk = 0; kk < 8; ++kk) {
            float acc = bf;
#pragma unroll
            for (int d = 0; d < 10; ++d) acc += sp[kk * 10 + d] * wf[d];
            myv[kk] = fmaxf(acc, 0.f);
        }
#pragma unroll
        for (int kk = 0; kk < 8; ++kk) x1[w][kbase + kk][ch] = myv[kk];

        float xv = 0.f;
        if (c >= 32) {
            xv = featsrc[(size_t)p * 32 + ch];
            if (SECOND) xv = fmaxf(xv * fa + fb, 0.f);
            fv[w][ch] = xv;
        }

        float col[16];
        if (c < 32) {
#pragma unroll
            for (int kk = 0; kk < 8; ++kk) col[kk] = myv[kk];
#pragma unroll
            for (int kk = 0; kk < 8; ++kk) col[8 + kk] = x1[w][8 + kk][ch];
        } else {
#pragma unroll
            for (int k = 0; k < 16; ++k) col[k] = xv;
        }

        float cst = 0.f;
#pragma unroll
        for (int dg = 8; dg < 16; ++dg) {
            float4 wv = *(const float4*)&wlt[c][dg * 4];
            float4 xvv = *(const float4*)&fv[w][(dg - 8) * 4];
            cst += xvv.x * wv.x + xvv.y * wv.y + xvv.z * wv.z + xvv.w * wv.w;
        }
        float scv[16];
#pragma unroll
        for (int k = 0; k < 16; ++k) scv[k] = cst;
        for (int dg = 0; dg < 8; ++dg) {
            float4 wv = *(const float4*)&wlt[c][dg * 4];
#pragma unroll
            for (int k = 0; k < 16; ++k) {
                float4 xvv = *(const float4*)&x1[w][k][dg * 4];
                scv[k] += xvv.x * wv.x + xvv.y * wv.y + xvv.z * wv.z + xvv.w * wv.w;
            }
        }
        float m = scv[0];
#pragma unroll
        for (int k = 1; k < 16; ++k) m = fmaxf(m, scv[k]);
        float sum = 0.f, p1 = 0.f;
#pragma unroll
        for (int k = 0; k < 16; ++k) { float e = __expf(scv[k] - m); sum += e; p1 += e * col[k]; }
        p1 /= sum;
        p1b[w][c] = p1;

        if (c < OUTC) {
            float acc = bmlp[c];
#pragma unroll
            for (int d = 0; d < 64; ++d) acc += p1b[w][d] * wm[d][c];
            preout[(size_t)p * OUTC + c] = acc;
            s += acc; s2 += (double)acc * acc;
        }
    }
    if (c < OUTC) { red[w][c][0] = s; red[w][c][1] = s2; }
    __syncthreads();
    if (t < OUTC) {
        double ts = red[0][t][0], ts2 = red[0][t][1];
        for (int g = 1; g < 4; ++g) { ts += red[g][t][0]; ts2 += red[g][t][1]; }
        atomicAdd(&stats[stat_base + t], ts);
        atomicAdd(&stats[stat_base + OUTC + t], ts2);
    }
}

// ---------------- K9: final mlp2 + shortcut BN + residual leaky + transposed write ----
__global__ __launch_bounds__(256) void k_out(const float* __restrict__ pre2,
                                             const float* __restrict__ short_pre,
                                             const float* __restrict__ W2, const float* __restrict__ b2,
                                             const double* __restrict__ stats,
                                             const float* __restrict__ g_a2, const float* __restrict__ be_a2,
                                             const float* __restrict__ g_s, const float* __restrict__ be_s,
                                             float* __restrict__ out) {
    __shared__ __align__(16) float w2[64][128];
    __shared__ float sc2[64], sh2[64], scs[128], shs[128], bb[128];
    int t = threadIdx.x;
    int pl = t & 31, seg = t >> 5;
    for (int e = t; e < 8192; e += 256) w2[e >> 7][e & 127] = W2[e];
    if (t < 64) { float2 p = fin_pair(stats, S_ATT2, t, 64, (double)BNTOT, g_a2, be_a2); sc2[t] = p.x; sh2[t] = p.y; }
    if (t >= 64 && t < 192) { int ch = t - 64; float2 p = fin_pair(stats, S_SHORT, ch, 128, (double)BNTOT, g_s, be_s); scs[ch] = p.x; shs[ch] = p.y; }
    if (t < 128) bb[t] = b2[t];
    __syncthreads();

    int p = blockIdx.x * 32 + pl;
    int b = p >> 13, n = p & 8191;
    const float* pr = pre2 + (size_t)p * 64;
    float xa[64];
#pragma unroll
    for (int c = 0; c < 64; c += 4) {
        float4 v = *(const float4*)&pr[c];
        xa[c + 0] = fmaxf(v.x * sc2[c + 0] + sh2[c + 0], 0.f);
        xa[c + 1] = fmaxf(v.y * sc2[c + 1] + sh2[c + 1], 0.f);
        xa[c + 2] = fmaxf(v.z * sc2[c + 2] + sh2[c + 2], 0.f);
        xa[c + 3] = fmaxf(v.w * sc2[c + 3] + sh2[c + 3], 0.f);
    }
    const float* shp = short_pre + (size_t)p * 128;
    int obase = seg * 16;
    for (int o = obase; o < obase + 16; o += 4) {
        float a0 = bb[o], a1 = bb[o + 1], a2 = bb[o + 2], a3 = bb[o + 3];
#pragma unroll
        for (int cc = 0; cc < 64; ++cc) {
            float4 wv = *(const float4*)&w2[cc][o];
            float x = xa[cc];
            a0 += x * wv.x; a1 += x * wv.y; a2 += x * wv.z; a3 += x * wv.w;
        }
        float4 sv = *(const float4*)&shp[o];
        float r0 = a0 + (sv.x * scs[o] + shs[o]);
        float r1 = a1 + (sv.y * scs[o + 1] + shs[o + 1]);
        float r2 = a2 + (sv.z * scs[o + 2] + shs[o + 2]);
        float r3 = a3 + (sv.w * scs[o + 3] + shs[o + 3]);
        out[((size_t)(b * C2 + o + 0)) * NN + n] = r0 >= 0.f ? r0 : 0.01f * r0;
        out[((size_t)(b * C2 + o + 1)) * NN + n] = r1 >= 0.f ? r1 : 0.01f * r1;
        out[((size_t)(b * C2 + o + 2)) * NN + n] = r2 >= 0.f ? r2 : 0.01f * r2;
        out[((size_t)(b * C2 + o + 3)) * NN + n] = r3 >= 0.f ? r3 : 0.01f * r3;
    }
}

extern "C" void kernel_launch(void* const* d_in, const int* in_sizes, int n_in,
                              void* d_out, int out_size, void* d_ws, size_t ws_size,
                              hipStream_t stream) {
    const float* coords    = (const float*)d_in[0];
    const float* features  = (const float*)d_in[1];
    const float* W_mlp1    = (const float*)d_in[2];
    const float* b_mlp1    = (const float*)d_in[3];
    const float* W_lse1    = (const float*)d_in[4];
    const float* b_lse1    = (const float*)d_in[5];
    const float* g_lse1    = (const float*)d_in[6];
    const float* be_lse1   = (const float*)d_in[7];
    const float* W_att1_lin= (const float*)d_in[8];
    const float* W_att1_mlp= (const float*)d_in[9];
    const float* b_att1_mlp= (const float*)d_in[10];
    const float* g_att1    = (const float*)d_in[11];
    const float* be_att1   = (const float*)d_in[12];
    const float* W_lse2    = (const float*)d_in[13];
    const float* b_lse2    = (const float*)d_in[14];
    const float* g_lse2    = (const float*)d_in[15];
    const float* be_lse2   = (const float*)d_in[16];
    const float* W_att2_lin= (const float*)d_in[17];
    const float* W_att2_mlp= (const float*)d_in[18];
    const float* b_att2_mlp= (const float*)d_in[19];
    const float* g_att2    = (const float*)d_in[20];
    const float* be_att2   = (const float*)d_in[21];
    const float* W_mlp2    = (const float*)d_in[22];
    const float* b_mlp2    = (const float*)d_in[23];
    const float* W_short   = (const float*)d_in[24];
    const float* b_short   = (const float*)d_in[25];
    const float* g_short   = (const float*)d_in[26];
    const float* be_short  = (const float*)d_in[27];

    float* ws = (float*)d_ws;
    float4* cp4      = (float4*)(ws + OFF_CP4);
    float* se        = ws + OFF_SE;
    float* xf        = ws + OFF_XF;
    float* short_pre = ws + OFF_SHORT;
    float* pre1      = ws + OFF_PRE1;
    float* pre2      = ws + OFF_PRE2;
    double* stats    = (double*)(ws + OFF_STATS);
    int* counts      = (int*)(ws + OFF_COUNTS);
    float* tbound    = ws + OFF_TB;
    int* code        = (int*)(ws + OFF_CODE);
    float4* cps      = (float4*)(ws + OFF_CPS);
    int* oidxArr     = (int*)(ws + OFF_OIDX);
    float* out       = (float*)d_out;

    // zero stats (576 doubles) + counts (8192 ints), contiguous
    hipMemsetAsync(stats, 0, S_TOTAL * 8 + 2 * NCELL * 4, stream);

    k_prep<<<BNTOT / 256, 256, 0, stream>>>(coords, cp4, code, counts);
    k_scan<<<1, 256, 0, stream>>>(counts);
    k_scatter<<<BNTOT / 256, 256, 0, stream>>>(cp4, code, counts, cps, oidxArr);
    k_seed<<<BNTOT / 256, 256, 0, stream>>>(cps, oidxArr, tbound);
    k_knn<<<1024, 256, 0, stream>>>(cp4, tbound, se);
    k_feat<<<512, 128, 0, stream>>>(features, W_mlp1, b_mlp1, W_short, b_short,
                                    xf, short_pre, stats);
    k_lse_stats<<<512, 256, 0, stream>>>(se, W_lse1, b_lse1, W_lse2, b_lse2, stats);
    k_att<32, false><<<1024, 256, 0, stream>>>(se, xf, W_lse1, b_lse1, W_att1_lin,
                                               W_att1_mlp, b_att1_mlp, stats,
                                               S_LSE1, 0, S_ATT1,
                                               g_lse1, be_lse1, nullptr, nullptr, pre1);
    k_att<64, true><<<1024, 256, 0, stream>>>(se, pre1, W_lse2, b_lse2, W_att2_lin,
                                              W_att2_mlp, b_att2_mlp, stats,
                                              S_LSE2, S_ATT1, S_ATT2,
                                              g_lse2, be_lse2, g_att1, be_att1, pre2);
    k_out<<<BNTOT / 32, 256, 0, stream>>>(pre2, short_pre, W_mlp2, b_mlp2, stats,
                                          g_att2, be_att2, g_short, be_short, out);
}

// Round 15
// 393.498 us; speedup vs baseline: 1.5400x; 1.1103x over previous
//
#include <hip/hip_runtime.h>
#include <cfloat>
#include <cmath>

#define DEV __device__ __forceinline__

constexpr int BB = 2, NN = 8192, KK = 16, CIN = 32, HH = 32, CO = 64, C2 = 128;
constexpr int BNTOT = BB * NN;        // 16384
constexpr int BNKROWS = BB * NN * KK; // 262144
constexpr float EPSF = 1e-6f;
constexpr int NCELL = 4096;           // 16^3 morton cells
constexpr int CAP = 128;              // survivor capacity per query

// stats indices (doubles): [sum.., sumsq..] per group
constexpr int S_LSE1 = 0, S_LSE2 = 64, S_ATT1 = 128, S_ATT2 = 192, S_SHORT = 320, S_TOTAL = 576;

// workspace layout (in floats)
constexpr size_t OFF_CP4   = 0;                                  // orig-order (x,y,z,sq): 16384*4
constexpr size_t OFF_SE    = OFF_CP4 + (size_t)BNTOT * 4;        // se (B,N,K,10)
constexpr size_t OFF_XF    = OFF_SE + (size_t)BNKROWS * 10;      // mlp1 out (B,N,32)
constexpr size_t OFF_SHORT = OFF_XF + (size_t)BNTOT * HH;        // shortcut pre-BN (B,N,128)
constexpr size_t OFF_PRE1  = OFF_SHORT + (size_t)BNTOT * C2;     // att1 pre-BN (B,N,32)
constexpr size_t OFF_PRE2  = OFF_PRE1 + (size_t)BNTOT * HH;      // att2 pre-BN (B,N,64)
constexpr size_t OFF_STATS = OFF_PRE2 + (size_t)BNTOT * CO;      // doubles x576 (even -> 8B aligned)
constexpr size_t OFF_COUNTS= OFF_STATS + 2 * S_TOTAL;            // int[2][4096]
constexpr size_t OFF_TB    = OFF_COUNTS + 2 * NCELL;             // float[16384] T_q bounds
// sort scratch overlaid in SHORT region (dead until k_feat, which runs after k_knn)
constexpr size_t OFF_CODE  = OFF_SHORT;                          // int[16384]
constexpr size_t OFF_CPS   = OFF_CODE + 16384;                   // float4[2][8192] + 4 pad
constexpr size_t OFF_OIDX  = OFF_CPS + (size_t)BNTOT * 4 + 16;   // int[2][8192]

DEV unsigned spr3(unsigned v) {
    return (v & 1u) | ((v & 2u) << 2) | ((v & 4u) << 4) | ((v & 8u) << 6);
}

// ---------------- K0: pack (x,y,z,sq) + morton cell + counts ----------------
__global__ __launch_bounds__(256) void k_prep(const float* __restrict__ coords,
                                              float4* __restrict__ cp4,
                                              int* __restrict__ code, int* __restrict__ counts) {
#pragma clang fp contract(off)
    int i = blockIdx.x * 256 + threadIdx.x;
    if (i >= BNTOT) return;
    float x = coords[3 * i], y = coords[3 * i + 1], z = coords[3 * i + 2];
    float sq = (x * x + y * y) + z * z;   // match numpy sum order, no FMA
    cp4[i] = make_float4(x, y, z, sq);
    const float inv = 16.f / 8.8f;
    int ix = min(15, max(0, (int)floorf((x + 4.4f) * inv)));
    int iy = min(15, max(0, (int)floorf((y + 4.4f) * inv)));
    int iz = min(15, max(0, (int)floorf((z + 4.4f) * inv)));
    unsigned m = spr3(ix) | (spr3(iy) << 1) | (spr3(iz) << 2);
    code[i] = (int)m;
    atomicAdd(&counts[((i >> 13) << 12) + m], 1);
}

// ---------------- K0b: exclusive prefix scan of counts (one block per batch) ----------------
__global__ __launch_bounds__(256) void k_scan(int* __restrict__ counts) {
    __shared__ int lds[256];
    int t = threadIdx.x;
    int base = blockIdx.x * NCELL;
    int v[16]; int s = 0;
#pragma unroll
    for (int k = 0; k < 16; ++k) { int tmp = counts[base + t * 16 + k]; v[k] = s; s += tmp; }
    lds[t] = s;
    __syncthreads();
    for (int o = 1; o < 256; o <<= 1) {
        int u = (t >= o) ? lds[t - o] : 0;
        __syncthreads();
        lds[t] += u;
        __syncthreads();
    }
    int off = lds[t] - s;   // exclusive
#pragma unroll
    for (int k = 0; k < 16; ++k) counts[base + t * 16 + k] = off + v[k];
}

// ---------------- K0c: scatter into sorted order ----------------
__global__ __launch_bounds__(256) void k_scatter(const float4* __restrict__ cp4,
                                                 const int* __restrict__ code,
                                                 int* __restrict__ cursor,
                                                 float4* __restrict__ cps, int* __restrict__ oidx) {
    int i = blockIdx.x * 256 + threadIdx.x;
    if (i >= BNTOT) return;
    int b = i >> 13, n = i & 8191;
    int c = code[i];
    int pos = atomicAdd(&cursor[(b << 12) + c], 1);
    cps[(b << 13) + pos] = cp4[i];
    oidx[(b << 13) + pos] = n;
}

DEV float dist2(float4 qc, float4 c) {
#pragma clang fp contract(off)
    float dot = (qc.x * c.x + qc.y * c.y) + qc.z * c.z;
    return (qc.w + c.w) - 2.0f * dot;   // exact jax/np expansion formula
}

// value-only sorted insert (16-deep): keeps 16 smallest values
DEV void insv16(float (&dl)[16], float d) {
    float dk = d;
#pragma unroll
    for (int r = 0; r < 16; ++r) {
        bool c = dk < dl[r];
        float td = dl[r];
        dl[r] = c ? dk : dl[r];
        dk = c ? td : dk;
    }
}

// lexicographic (d, idx) sorted insert
DEV void ins16_lex(float (&dl)[16], int (&il)[16], float d, int id) {
    float dk = d; int jk = id;
#pragma unroll
    for (int r = 0; r < 16; ++r) {
        bool c = (dk < dl[r]) || (dk == dl[r] && jk < il[r]);
        float td = dl[r]; int ti = il[r];
        dl[r] = c ? dk : dl[r]; il[r] = c ? jk : il[r];
        dk = c ? td : dk; jk = c ? ti : jk;
    }
}

// ---------------- K0d: per-query threshold bound from 256 Morton-window neighbors ----
// T_q = 16th-smallest exact d2 among the query's 256 sorted-order neighbors.
// Subset 16th order-stat >= global 16th order-stat -> EXACT upper bound, no margin.
// Parallelized 4 lanes/query (each scans 64 of the window), shfl_xor value-merge.
__global__ __launch_bounds__(256) void k_seed(const float4* __restrict__ cps,
                                              const int* __restrict__ oidx,
                                              float* __restrict__ tbound) {
    int t = threadIdx.x;
    int ql = t >> 2, sub = t & 3;
    int b = blockIdx.x >> 7;                  // 128 blocks per batch (64 queries each)
    int p = ((blockIdx.x & 127) << 6) + ql;   // sorted position within batch
    const float4* cb_ = cps + ((size_t)b << 13);
    float4 qc = cb_[p];
    int s = p - 128;
    s = s < 0 ? 0 : (s > NN - 256 ? NN - 256 : s);
    s += sub * 64;
    float dl[16];
#pragma unroll
    for (int i = 0; i < 16; ++i) dl[i] = FLT_MAX;
    for (int j = 0; j < 64; j += 4) {
        float4 c0 = cb_[s + j], c1 = cb_[s + j + 1], c2 = cb_[s + j + 2], c3 = cb_[s + j + 3];
        float d0 = dist2(qc, c0), d1 = dist2(qc, c1), d2v = dist2(qc, c2), d3 = dist2(qc, c3);
        if (d0 < dl[15]) insv16(dl, d0);
        if (d1 < dl[15]) insv16(dl, d1);
        if (d2v < dl[15]) insv16(dl, d2v);
        if (d3 < dl[15]) insv16(dl, d3);
    }
    // merge the 4 sub-lists (lanes 4q..4q+3 are in the same wave)
#pragma unroll
    for (int o = 1; o < 4; o <<= 1) {
        float dd[16];
#pragma unroll
        for (int i = 0; i < 16; ++i) dd[i] = __shfl_xor(dl[i], o);
#pragma unroll
        for (int i = 0; i < 16; ++i) if (dd[i] < dl[15]) insv16(dl, dd[i]);
    }
    if (sub == 0) tbound[(b << 13) + oidx[(b << 13) + p]] = dl[15];
}

// ---------------- K1: LDS-staged bound-filter KNN + exact select + spatial encoding ----
// grid 1024 = 2 batches x 512 groups of 16 queries; block 256; thread: query=t&15,
// partition=t>>4 scans candidates {part + 16j} of each LDS tile.
// Main scan: predicate d <= T_q (exact precomputed bound) -> append survivor to LDS.
// Overflow (scnt > CAP, loose T at Morton jumps) handled by ITERATED refine (<=3
// passes): T' = 16th-smallest among kept CAP survivors (real points -> exact bound,
// expected rank shrinks ~8x per pass), block-cooperative coalesced rescan. R14's
// single pass left M>~1000 queries still overflowing -> 38K-cycle serial fallback
// stragglers set kernel time. Serial exact scan remains as unreachable last resort.
// All paths give exact lex-(d2,idx) top-16 == jax top_k; final survivor set is the
// full ball {d <= T'} whenever <=CAP -> output set-determined -> deterministic.
__global__ __launch_bounds__(256) void k_knn(const float4* __restrict__ cp4,
                                             const float* __restrict__ tbound,
                                             float* __restrict__ se) {
    __shared__ __align__(16) float4 tile[1024];   // 16 KB
    __shared__ uint2 surv[16][CAP + 1];           // 16.5 KB (+1 pad)
    __shared__ int scnt[16];
    __shared__ float sd[16][17];
    __shared__ int   si[16][17];
    __shared__ int nof;
    __shared__ float t2s;

    int t = threadIdx.x;
    int b = blockIdx.x >> 9;
    int qbase = (blockIdx.x & 511) * 16;
    int ql = t & 15, part = t >> 4;
    int wv = t >> 6, lane = t & 63;
    const float4* cp = cp4 + ((size_t)b << 13);
    int q = qbase + ql;
    float4 qc = cp[q];
    float T = tbound[(b << 13) + q];

    if (t < 16) scnt[t] = 0;

    // pipeline: load tile 0 into registers
    float4 r0 = cp[t], r1 = cp[t + 256], r2 = cp[t + 512], r3 = cp[t + 768];

    for (int tb = 0; tb < 8192; tb += 1024) {
        __syncthreads();                    // previous scan done (and scnt init on first iter)
        tile[t] = r0; tile[t + 256] = r1; tile[t + 512] = r2; tile[t + 768] = r3;
        if (tb + 1024 < 8192) {             // issue next tile's loads; latency hides under scan
            const float4* nx = cp + tb + 1024;
            r0 = nx[t]; r1 = nx[t + 256]; r2 = nx[t + 512]; r3 = nx[t + 768];
        }
        __syncthreads();
        for (int j = 0; j < 64; j += 4) {
            float4 c0 = tile[part + 16 * j];
            float4 c1 = tile[part + 16 * (j + 1)];
            float4 c2 = tile[part + 16 * (j + 2)];
            float4 c3 = tile[part + 16 * (j + 3)];
            float d0 = dist2(qc, c0), d1 = dist2(qc, c1), d2v = dist2(qc, c2), d3 = dist2(qc, c3);
            bool p0 = d0 <= T, p1 = d1 <= T, p2 = d2v <= T, p3 = d3 <= T;
            if (__any(p0 | p1 | p2 | p3)) {
                int jb = tb + part;
                if (p0) { int pos = atomicAdd(&scnt[ql], 1); if (pos < CAP) surv[ql][pos] = make_uint2(__float_as_uint(d0), (unsigned)(jb + 16 * j)); }
                if (p1) { int pos = atomicAdd(&scnt[ql], 1); if (pos < CAP) surv[ql][pos] = make_uint2(__float_as_uint(d1), (unsigned)(jb + 16 * (j + 1))); }
                if (p2) { int pos = atomicAdd(&scnt[ql], 1); if (pos < CAP) surv[ql][pos] = make_uint2(__float_as_uint(d2v), (unsigned)(jb + 16 * (j + 2))); }
                if (p3) { int pos = atomicAdd(&scnt[ql], 1); if (pos < CAP) surv[ql][pos] = make_uint2(__float_as_uint(d3), (unsigned)(jb + 16 * (j + 3))); }
            }
        }
    }
    __syncthreads();

    // ---- iterated refine: overflowed queries get tighter exact bounds + coalesced rescans ----
    for (int rpass = 0; rpass < 3; ++rpass) {
        if (t == 0) nof = 0;
        __syncthreads();
        if (t < 16 && scnt[t] > CAP) atomicAdd(&nof, 1);
        __syncthreads();
        if (!nof) break;                        // uniform (post-barrier LDS read)
        for (int q2 = 0; q2 < 16; ++q2) {
            int n0 = scnt[q2];                  // uniform (post-barrier)
            __syncthreads();                    // all read n0 before any reset
            if (n0 <= CAP) continue;            // uniform branch
            if (t == 0) {                       // T' = 16th among kept survivors (real points -> exact bound)
                float dl[16];
#pragma unroll
                for (int i = 0; i < 16; ++i) dl[i] = FLT_MAX;
                for (int s2 = 0; s2 < CAP; ++s2) {
                    float d = __uint_as_float(surv[q2][s2].x);
                    if (d < dl[15]) insv16(dl, d);
                }
                t2s = dl[15];
                scnt[q2] = 0;
            }
            __syncthreads();
            float T2 = t2s;
            float4 qc2 = cp[qbase + q2];
            int jb = t * 32;                    // block-cooperative coalesced rescan
            for (int j = jb; j < jb + 32; j += 4) {
                float4 c0 = cp[j], c1 = cp[j + 1], c2 = cp[j + 2], c3 = cp[j + 3];
                float d0 = dist2(qc2, c0), d1 = dist2(qc2, c1), d2v = dist2(qc2, c2), d3 = dist2(qc2, c3);
                if (d0 <= T2) { int pos = atomicAdd(&scnt[q2], 1); if (pos < CAP) surv[q2][pos] = make_uint2(__float_as_uint(d0), (unsigned)j); }
                if (d1 <= T2) { int pos = atomicAdd(&scnt[q2], 1); if (pos < CAP) surv[q2][pos] = make_uint2(__float_as_uint(d1), (unsigned)(j + 1)); }
                if (d2v <= T2) { int pos = atomicAdd(&scnt[q2], 1); if (pos < CAP) surv[q2][pos] = make_uint2(__float_as_uint(d2v), (unsigned)(j + 2)); }
                if (d3 <= T2) { int pos = atomicAdd(&scnt[q2], 1); if (pos < CAP) surv[q2][pos] = make_uint2(__float_as_uint(d3), (unsigned)(j + 3)); }
            }
            __syncthreads();
        }
    }

    // last-resort: exact wave-parallel top-16 for still-overflowed queries (unreachable in practice)
    for (int q2 = wv; q2 < 16; q2 += 4) {
        if (scnt[q2] > CAP) {
            float4 qc2 = cp[qbase + q2];
            float dl[16]; int il[16];
#pragma unroll
            for (int i = 0; i < 16; ++i) { dl[i] = FLT_MAX; il[i] = 0x7fffffff; }
            for (int i = 0; i < 128; ++i) {       // coalesced: lane + 64*i
                int j = lane + (i << 6);
                float d = dist2(qc2, cp[j]);
                if (d < dl[15] || (d == dl[15] && j < il[15])) ins16_lex(dl, il, d, j);
            }
            for (int o = 1; o < 64; o <<= 1) {    // butterfly union-merge
                float dd[16]; int ii[16];
#pragma unroll
                for (int i = 0; i < 16; ++i) { dd[i] = __shfl_xor(dl[i], o); ii[i] = __shfl_xor(il[i], o); }
#pragma unroll
                for (int i = 0; i < 16; ++i) {
                    if (dd[i] < dl[15] || (dd[i] == dl[15] && ii[i] < il[15])) ins16_lex(dl, il, dd[i], ii[i]);
                }
            }
            if (lane == 0) {
#pragma unroll
                for (int i = 0; i < 16; ++i) { sd[q2][i] = dl[i]; si[q2][i] = il[i]; }
            }
        }
    }

    // phase C: exact lex top-16 of survivors (one thread per query, non-overflowed only)
    if (t < 16 && scnt[t] <= CAP) {
        int n = scnt[t];
        float dl[16]; int il[16];
#pragma unroll
        for (int i = 0; i < 16; ++i) { dl[i] = FLT_MAX; il[i] = 0x7fffffff; }
        for (int s2 = 0; s2 < n; ++s2) {
            uint2 v = surv[t][s2];
            float d = __uint_as_float(v.x); int id = (int)v.y;
            if (d < dl[15] || (d == dl[15] && id < il[15])) ins16_lex(dl, il, d, id);
        }
#pragma unroll
        for (int i = 0; i < 16; ++i) { sd[t][i] = dl[i]; si[t][i] = il[i]; }
    }
    __syncthreads();

    // epilogue: 256 threads write 256 se rows (one (q,k) slot each)
    {
        int qq = t >> 4, k = t & 15;
        float d2s = sd[qq][k]; int id = si[qq][k];
        float4 qc2 = cp[qbase + qq];
        float4 nb = cp[id];
        float dist = sqrtf(fmaxf(d2s, 1e-12f));
        float* sp = se + ((size_t)(b * NN + qbase + qq) * KK + k) * 10;
        sp[0] = qc2.x; sp[1] = qc2.y; sp[2] = qc2.z;
        sp[3] = nb.x;  sp[4] = nb.y;  sp[5] = nb.z;
        sp[6] = qc2.x - nb.x; sp[7] = qc2.y - nb.y; sp[8] = qc2.z - nb.z;
        sp[9] = dist;
    }
}

// ---------------- K2: mlp1 + shortcut linear + shortcut BN stats ----------------
__global__ __launch_bounds__(128) void k_feat(const float* __restrict__ feat,
                                              const float* __restrict__ Wm1, const float* __restrict__ bm1,
                                              const float* __restrict__ Wsh, const float* __restrict__ bsh,
                                              float* __restrict__ xf, float* __restrict__ short_pre,
                                              double* __restrict__ stats) {
    __shared__ float fl[32][33];
    int t = threadIdx.x;
    int pbase = blockIdx.x * 32;
    float wcol[32];
#pragma unroll
    for (int i = 0; i < 32; ++i) wcol[i] = Wsh[i * C2 + t];
    float wm[32];
    if (t < 32) {
#pragma unroll
        for (int i = 0; i < 32; ++i) wm[i] = Wm1[i * HH + t];
    }
    float bs = bsh[t];
    float bm = (t < 32) ? bm1[t] : 0.f;
    double s = 0.0, s2 = 0.0;

    for (int e = t; e < 1024; e += 128) {
        int p = e >> 5, i = e & 31;
        fl[p][i] = feat[(size_t)(pbase + p) * CIN + i];
    }
    __syncthreads();
    for (int p = 0; p < 32; ++p) {
        float acc = bs;
#pragma unroll
        for (int i = 0; i < 32; ++i) acc += fl[p][i] * wcol[i];
        int gp = pbase + p;
        short_pre[(size_t)gp * C2 + t] = acc;
        s += acc; s2 += (double)acc * acc;
        if (t < 32) {
            float xv = bm;
#pragma unroll
            for (int i = 0; i < 32; ++i) xv += fl[p][i] * wm[i];
            xf[(size_t)gp * HH + t] = xv >= 0.f ? xv : 0.2f * xv;
        }
    }
    atomicAdd(&stats[S_SHORT + t], s);
    atomicAdd(&stats[S_SHORT + C2 + t], s2);
}

// ---------------- K3: lse1+lse2 linear BN stats (LDS-staged) ----------------
__global__ __launch_bounds__(256) void k_lse_stats(const float* __restrict__ se,
                                                   const float* __restrict__ W1, const float* __restrict__ b1,
                                                   const float* __restrict__ W2, const float* __restrict__ b2,
                                                   double* __restrict__ stats) {
    __shared__ float srows[256][10];
    __shared__ double red[4][64][2];
    int t = threadIdx.x;
    int c = t & 63, grp = t >> 6;
    int ch = c & 31; bool second = c >= 32;
    const float* W = second ? W2 : W1;
    float wcol[10];
#pragma unroll
    for (int d = 0; d < 10; ++d) wcol[d] = W[d * HH + ch];
    float bb = second ? b2[ch] : b1[ch];
    double s = 0.0, s2 = 0.0;
    int rbase = blockIdx.x * 512;

    for (int tile = 0; tile < 2; ++tile) {
        __syncthreads();
        const float* src = se + (size_t)(rbase + tile * 256) * 10;
        for (int e = t; e < 2560; e += 256) srows[e / 10][e % 10] = src[e];
        __syncthreads();
        int r0 = grp * 64;
        for (int r = r0; r < r0 + 64; ++r) {
            float acc = bb;
#pragma unroll
            for (int d = 0; d < 10; ++d) acc += srows[r][d] * wcol[d];
            s += acc; s2 += (double)acc * acc;
        }
    }
    red[grp][c][0] = s; red[grp][c][1] = s2;
    __syncthreads();
    if (grp == 0) {
        for (int g = 1; g < 4; ++g) { s += red[g][c][0]; s2 += red[g][c][1]; }
        int base = second ? S_LSE2 : S_LSE1;
        atomicAdd(&stats[base + ch], s);
        atomicAdd(&stats[base + 32 + ch], s2);
    }
}

// BN scale/shift from raw stats (computed redundantly in consumer prologues)
DEV float2 fin_pair(const double* stats, int sbase, int ch, int nch, double M,
                    const float* g, const float* be) {
    double mean = stats[sbase + ch] / M;
    double var = stats[sbase + nch + ch] / M - mean * mean;
    double scd = (double)g[ch] / sqrt(var + (double)EPSF);
    return make_float2((float)scd, (float)((double)be[ch] - mean * scd));
}

// ---------------- K5/K7: fused LocSE + attentive pooling + MLP ----------------
template <int OUTC, bool SECOND>
__global__ __launch_bounds__(256) void k_att(const float* __restrict__ se,
                                             const float* __restrict__ featsrc,
                                             const float* __restrict__ Wlse, const float* __restrict__ blse,
                                             const float* __restrict__ Wlin,
                                             const float* __restrict__ Wmlp, const float* __restrict__ bmlp,
                                             double* __restrict__ stats, int lse_sbase, int feat_sbase, int stat_base,
                                             const float* __restrict__ g_lse, const float* __restrict__ be_lse,
                                             const float* __restrict__ g_f, const float* __restrict__ be_f,
                                             float* __restrict__ preout) {
    __shared__ __align__(16) float wlt[64][68];
    __shared__ float wm[64][OUTC];
    __shared__ __align__(16) float x1[4][16][40];
    __shared__ float fv[4][32];
    __shared__ float p1b[4][64];
    __shared__ double red[4][OUTC][2];

    int t = threadIdx.x, w = t >> 6, c = t & 63;
    int ch = c & 31, half = c >> 5;
    for (int e = t; e < 4096; e += 256) wlt[e & 63][e >> 6] = Wlin[e];
    for (int e = t; e < 64 * OUTC; e += 256) wm[e / OUTC][e % OUTC] = Wmlp[e];

    float wf[10]; float bf;
    {
        float2 p = fin_pair(stats, lse_sbase, ch, 32, (double)BNKROWS, g_lse, be_lse);
#pragma unroll
        for (int d = 0; d < 10; ++d) wf[d] = Wlse[d * 32 + ch] * p.x;
        bf = blse[ch] * p.x + p.y;
    }
    float fa = 1.f, fb = 0.f;
    if (SECOND && c >= 32) {
        float2 p = fin_pair(stats, feat_sbase, ch, 32, (double)BNTOT, g_f, be_f);
        fa = p.x; fb = p.y;
    }
    double s = 0.0, s2 = 0.0;
    __syncthreads();

    for (int i = 0; i < 4; ++i) {
        int p = blockIdx.x * 16 + w * 4 + i;

        int kbase = half * 8;
        const float* sp = se + (size_t)p * (KK * 10) + kbase * 10;
        float myv[8];
#pragma unroll
        for (int kk = 0; kk < 8; ++kk) {
            float acc = bf;
#pragma unroll
            for (int d = 0; d < 10; ++d) acc += sp[kk * 10 + d] * wf[d];
            myv[kk] = fmaxf(acc, 0.f);
        }
#pragma unroll
        for (int kk = 0; kk < 8; ++kk) x1[w][kbase + kk][ch] = myv[kk];

        float xv = 0.f;
        if (c >= 32) {
            xv = featsrc[(size_t)p * 32 + ch];
            if (SECOND) xv = fmaxf(xv * fa + fb, 0.f);
            fv[w][ch] = xv;
        }

        float col[16];
        if (c < 32) {
#pragma unroll
            for (int kk = 0; kk < 8; ++kk) col[kk] = myv[kk];
#pragma unroll
            for (int kk = 0; kk < 8; ++kk) col[8 + kk] = x1[w][8 + kk][ch];
        } else {
#pragma unroll
            for (int k = 0; k < 16; ++k) col[k] = xv;
        }

        float cst = 0.f;
#pragma unroll
        for (int dg = 8; dg < 16; ++dg) {
            float4 wv = *(const float4*)&wlt[c][dg * 4];
            float4 xvv = *(const float4*)&fv[w][(dg - 8) * 4];
            cst += xvv.x * wv.x + xvv.y * wv.y + xvv.z * wv.z + xvv.w * wv.w;
        }
        float scv[16];
#pragma unroll
        for (int k = 0; k < 16; ++k) scv[k] = cst;
        for (int dg = 0; dg < 8; ++dg) {
            float4 wv = *(const float4*)&wlt[c][dg * 4];
#pragma unroll
            for (int k = 0; k < 16; ++k) {
                float4 xvv = *(const float4*)&x1[w][k][dg * 4];
                scv[k] += xvv.x * wv.x + xvv.y * wv.y + xvv.z * wv.z + xvv.w * wv.w;
            }
        }
        float m = scv[0];
#pragma unroll
        for (int k = 1; k < 16; ++k) m = fmaxf(m, scv[k]);
        float sum = 0.f, p1 = 0.f;
#pragma unroll
        for (int k = 0; k < 16; ++k) { float e = __expf(scv[k] - m); sum += e; p1 += e * col[k]; }
        p1 /= sum;
        p1b[w][c] = p1;

        if (c < OUTC) {
            float acc = bmlp[c];
#pragma unroll
            for (int d = 0; d < 64; ++d) acc += p1b[w][d] * wm[d][c];
            preout[(size_t)p * OUTC + c] = acc;
            s += acc; s2 += (double)acc * acc;
        }
    }
    if (c < OUTC) { red[w][c][0] = s; red[w][c][1] = s2; }
    __syncthreads();
    if (t < OUTC) {
        double ts = red[0][t][0], ts2 = red[0][t][1];
        for (int g = 1; g < 4; ++g) { ts += red[g][t][0]; ts2 += red[g][t][1]; }
        atomicAdd(&stats[stat_base + t], ts);
        atomicAdd(&stats[stat_base + OUTC + t], ts2);
    }
}

// ---------------- K9: final mlp2 + shortcut BN + residual leaky + transposed write ----
__global__ __launch_bounds__(256) void k_out(const float* __restrict__ pre2,
                                             const float* __restrict__ short_pre,
                                             const float* __restrict__ W2, const float* __restrict__ b2,
                                             const double* __restrict__ stats,
                                             const float* __restrict__ g_a2, const float* __restrict__ be_a2,
                                             const float* __restrict__ g_s, const float* __restrict__ be_s,
                                             float* __restrict__ out) {
    __shared__ __align__(16) float w2[64][128];
    __shared__ float sc2[64], sh2[64], scs[128], shs[128], bb[128];
    int t = threadIdx.x;
    int pl = t & 31, seg = t >> 5;
    for (int e = t; e < 8192; e += 256) w2[e >> 7][e & 127] = W2[e];
    if (t < 64) { float2 p = fin_pair(stats, S_ATT2, t, 64, (double)BNTOT, g_a2, be_a2); sc2[t] = p.x; sh2[t] = p.y; }
    if (t >= 64 && t < 192) { int ch = t - 64; float2 p = fin_pair(stats, S_SHORT, ch, 128, (double)BNTOT, g_s, be_s); scs[ch] = p.x; shs[ch] = p.y; }
    if (t < 128) bb[t] = b2[t];
    __syncthreads();

    int p = blockIdx.x * 32 + pl;
    int b = p >> 13, n = p & 8191;
    const float* pr = pre2 + (size_t)p * 64;
    float xa[64];
#pragma unroll
    for (int c = 0; c < 64; c += 4) {
        float4 v = *(const float4*)&pr[c];
        xa[c + 0] = fmaxf(v.x * sc2[c + 0] + sh2[c + 0], 0.f);
        xa[c + 1] = fmaxf(v.y * sc2[c + 1] + sh2[c + 1], 0.f);
        xa[c + 2] = fmaxf(v.z * sc2[c + 2] + sh2[c + 2], 0.f);
        xa[c + 3] = fmaxf(v.w * sc2[c + 3] + sh2[c + 3], 0.f);
    }
    const float* shp = short_pre + (size_t)p * 128;
    int obase = seg * 16;
    for (int o = obase; o < obase + 16; o += 4) {
        float a0 = bb[o], a1 = bb[o + 1], a2 = bb[o + 2], a3 = bb[o + 3];
#pragma unroll
        for (int cc = 0; cc < 64; ++cc) {
            float4 wv = *(const float4*)&w2[cc][o];
            float x = xa[cc];
            a0 += x * wv.x; a1 += x * wv.y; a2 += x * wv.z; a3 += x * wv.w;
        }
        float4 sv = *(const float4*)&shp[o];
        float r0 = a0 + (sv.x * scs[o] + shs[o]);
        float r1 = a1 + (sv.y * scs[o + 1] + shs[o + 1]);
        float r2 = a2 + (sv.z * scs[o + 2] + shs[o + 2]);
        float r3 = a3 + (sv.w * scs[o + 3] + shs[o + 3]);
        out[((size_t)(b * C2 + o + 0)) * NN + n] = r0 >= 0.f ? r0 : 0.01f * r0;
        out[((size_t)(b * C2 + o + 1)) * NN + n] = r1 >= 0.f ? r1 : 0.01f * r1;
        out[((size_t)(b * C2 + o + 2)) * NN + n] = r2 >= 0.f ? r2 : 0.01f * r2;
        out[((size_t)(b * C2 + o + 3)) * NN + n] = r3 >= 0.f ? r3 : 0.01f * r3;
    }
}

extern "C" void kernel_launch(void* const* d_in, const int* in_sizes, int n_in,
                              void* d_out, int out_size, void* d_ws, size_t ws_size,
                              hipStream_t stream) {
    const float* coords    = (const float*)d_in[0];
    const float* features  = (const float*)d_in[1];
    const float* W_mlp1    = (const float*)d_in[2];
    const float* b_mlp1    = (const float*)d_in[3];
    const float* W_lse1    = (const float*)d_in[4];
    const float* b_lse1    = (const float*)d_in[5];
    const float* g_lse1    = (const float*)d_in[6];
    const float* be_lse1   = (const float*)d_in[7];
    const float* W_att1_lin= (const float*)d_in[8];
    const float* W_att1_mlp= (const float*)d_in[9];
    const float* b_att1_mlp= (const float*)d_in[10];
    const float* g_att1    = (const float*)d_in[11];
    const float* be_att1   = (const float*)d_in[12];
    const float* W_lse2    = (const float*)d_in[13];
    const float* b_lse2    = (const float*)d_in[14];
    const float* g_lse2    = (const float*)d_in[15];
    const float* be_lse2   = (const float*)d_in[16];
    const float* W_att2_lin= (const float*)d_in[17];
    const float* W_att2_mlp= (const float*)d_in[18];
    const float* b_att2_mlp= (const float*)d_in[19];
    const float* g_att2    = (const float*)d_in[20];
    const float* be_att2   = (const float*)d_in[21];
    const float* W_mlp2    = (const float*)d_in[22];
    const float* b_mlp2    = (const float*)d_in[23];
    const float* W_short   = (const float*)d_in[24];
    const float* b_short   = (const float*)d_in[25];
    const float* g_short   = (const float*)d_in[26];
    const float* be_short  = (const float*)d_in[27];

    float* ws = (float*)d_ws;
    float4* cp4      = (float4*)(ws + OFF_CP4);
    float* se        = ws + OFF_SE;
    float* xf        = ws + OFF_XF;
    float* short_pre = ws + OFF_SHORT;
    float* pre1      = ws + OFF_PRE1;
    float* pre2      = ws + OFF_PRE2;
    double* stats    = (double*)(ws + OFF_STATS);
    int* counts      = (int*)(ws + OFF_COUNTS);
    float* tbound    = ws + OFF_TB;
    int* code        = (int*)(ws + OFF_CODE);
    float4* cps      = (float4*)(ws + OFF_CPS);
    int* oidxArr     = (int*)(ws + OFF_OIDX);
    float* out       = (float*)d_out;

    // zero stats (576 doubles) + counts (8192 ints), contiguous
    hipMemsetAsync(stats, 0, S_TOTAL * 8 + 2 * NCELL * 4, stream);

    k_prep<<<BNTOT / 256, 256, 0, stream>>>(coords, cp4, code, counts);
    k_scan<<<2, 256, 0, stream>>>(counts);
    k_scatter<<<BNTOT / 256, 256, 0, stream>>>(cp4, code, counts, cps, oidxArr);
    k_seed<<<BNTOT / 64, 256, 0, stream>>>(cps, oidxArr, tbound);
    k_knn<<<1024, 256, 0, stream>>>(cp4, tbound, se);
    k_feat<<<512, 128, 0, stream>>>(features, W_mlp1, b_mlp1, W_short, b_short,
                                    xf, short_pre, stats);
    k_lse_stats<<<512, 256, 0, stream>>>(se, W_lse1, b_lse1, W_lse2, b_lse2, stats);
    k_att<32, false><<<1024, 256, 0, stream>>>(se, xf, W_lse1, b_lse1, W_att1_lin,
                                               W_att1_mlp, b_att1_mlp, stats,
                                               S_LSE1, 0, S_ATT1,
                                               g_lse1, be_lse1, nullptr, nullptr, pre1);
    k_att<64, true><<<1024, 256, 0, stream>>>(se, pre1, W_lse2, b_lse2, W_att2_lin,
                                              W_att2_mlp, b_att2_mlp, stats,
                                              S_LSE2, S_ATT1, S_ATT2,
                                              g_lse2, be_lse2, g_att1, be_att1, pre2);
    k_out<<<BNTOT / 32, 256, 0, stream>>>(pre2, short_pre, W_mlp2, b_mlp2, stats,
                                          g_att2, be_att2, g_short, be_short, out);
}